// Round 2
// baseline (683.124 us; speedup 1.0000x reference)
//
#include <hip/hip_runtime.h>
#include <hip/hip_bf16.h>

// ---------------- problem constants ----------------
#define T_TOK 2048
#define H_DIM 1024
#define F_DIM 4096
#define E_NUM 16
#define K_TOP 4

typedef float    floatx4 __attribute__((ext_vector_type(4)));
typedef _Float16 f16x8   __attribute__((ext_vector_type(8)));

// ---------------- ws layout (bytes) ----------------
#define XH_OFF    ((size_t)0)                    // 2048*1024 f16 = 4 MB
#define HBUF_OFF  ((size_t)(8ull*1024*1024))     // 8192*4096 f16 = 64 MB; first 8 MB doubles as hrf (f32) before expert GEMM1
#define YBUF_OFF  ((size_t)(72ull*1024*1024))    // 8192*1024 f32 = 32 MB
#define LOGIT_OFF ((size_t)(104ull*1024*1024))   // 2048*16 f32
#define TOPI_OFF  (LOGIT_OFF + 128ull*1024)
#define TOPW_OFF  (TOPI_OFF + 32ull*1024)
#define CNT_OFF   (TOPW_OFF + 32ull*1024)
#define OFFS_OFF  (CNT_OFF + 256ull)
#define CUR_OFF   (OFFS_OFF + 256ull)
#define TOKS_OFF  (CUR_OFF + 256ull)
#define WSL_OFF   (TOKS_OFF + 32ull*1024)
#define STK_OFF   (WSL_OFF + 32ull*1024)

// ---------------- small kernels ----------------
__global__ void zero_counts_kernel(int* counts) {
  if (threadIdx.x < E_NUM) counts[threadIdx.x] = 0;
}

__global__ void cast_x_kernel(const float* __restrict__ x, _Float16* __restrict__ xh) {
  int i = blockIdx.x * 256 + threadIdx.x;       // 8 elems each
  const floatx4* xin = reinterpret_cast<const floatx4*>(x) + (size_t)i * 2;
  floatx4 a = xin[0], b = xin[1];
  f16x8 o;
  o[0] = (_Float16)a[0]; o[1] = (_Float16)a[1]; o[2] = (_Float16)a[2]; o[3] = (_Float16)a[3];
  o[4] = (_Float16)b[0]; o[5] = (_Float16)b[1]; o[6] = (_Float16)b[2]; o[7] = (_Float16)b[3];
  *reinterpret_cast<f16x8*>(xh + (size_t)i * 8) = o;
}

// ---- router GEMM1, near-fp32 via 3-term fp16 split: hrf = relu(x @ Wr1 + br1), fp32 out ----
__global__ __launch_bounds__(256) void router_gemm1_kernel(
    const float* __restrict__ x, const float* __restrict__ Wr1,
    const float* __restrict__ br1, float* __restrict__ hrf) {
  int m0 = blockIdx.y * 64, n0 = blockIdx.x * 64;
  __shared__ _Float16 Ah[64][40];
  __shared__ _Float16 Al[64][40];
  __shared__ _Float16 Bh[64][40];
  __shared__ _Float16 Bl[64][40];
  int tid = threadIdx.x;
  int arow = tid >> 2, achk = tid & 3;
  const float* Arow = x + (size_t)(m0 + arow) * H_DIM + achk * 8;
  int brow = tid >> 3, bq = tid & 7;

  floatx4 acc[2][2];
#pragma unroll
  for (int i = 0; i < 2; i++)
#pragma unroll
    for (int j = 0; j < 2; j++) acc[i][j] = (floatx4){0.f, 0.f, 0.f, 0.f};

  int wv = tid >> 6, lane = tid & 63;
  int wm = wv >> 1, wn = wv & 1;
  int lrow = lane & 15, lk = (lane >> 4) * 8;

  for (int k0 = 0; k0 < H_DIM; k0 += 32) {
    floatx4 a0 = *reinterpret_cast<const floatx4*>(Arow + k0);
    floatx4 a1 = *reinterpret_cast<const floatx4*>(Arow + k0 + 4);
    f16x8 hv, lv;
#pragma unroll
    for (int j = 0; j < 4; j++) {
      _Float16 hi = (_Float16)a0[j]; hv[j] = hi; lv[j] = (_Float16)(a0[j] - (float)hi);
      _Float16 hi2 = (_Float16)a1[j]; hv[4 + j] = hi2; lv[4 + j] = (_Float16)(a1[j] - (float)hi2);
    }
    *reinterpret_cast<f16x8*>(&Ah[arow][achk * 8]) = hv;
    *reinterpret_cast<f16x8*>(&Al[arow][achk * 8]) = lv;
    const float* wp = Wr1 + (size_t)(k0 + brow) * H_DIM + n0 + bq * 4;
    floatx4 w0 = *reinterpret_cast<const floatx4*>(wp);
    floatx4 w1 = *reinterpret_cast<const floatx4*>(wp + 32);
#pragma unroll
    for (int i = 0; i < 4; i++) {
      _Float16 h0 = (_Float16)w0[i];
      Bh[bq * 4 + i][brow] = h0; Bl[bq * 4 + i][brow] = (_Float16)(w0[i] - (float)h0);
      _Float16 h1 = (_Float16)w1[i];
      Bh[32 + bq * 4 + i][brow] = h1; Bl[32 + bq * 4 + i][brow] = (_Float16)(w1[i] - (float)h1);
    }
    __syncthreads();

    f16x8 ah0 = *reinterpret_cast<const f16x8*>(&Ah[32 * wm + lrow][lk]);
    f16x8 ah1 = *reinterpret_cast<const f16x8*>(&Ah[32 * wm + 16 + lrow][lk]);
    f16x8 al0 = *reinterpret_cast<const f16x8*>(&Al[32 * wm + lrow][lk]);
    f16x8 al1 = *reinterpret_cast<const f16x8*>(&Al[32 * wm + 16 + lrow][lk]);
    f16x8 bh0 = *reinterpret_cast<const f16x8*>(&Bh[32 * wn + lrow][lk]);
    f16x8 bh1 = *reinterpret_cast<const f16x8*>(&Bh[32 * wn + 16 + lrow][lk]);
    f16x8 bl0 = *reinterpret_cast<const f16x8*>(&Bl[32 * wn + lrow][lk]);
    f16x8 bl1 = *reinterpret_cast<const f16x8*>(&Bl[32 * wn + 16 + lrow][lk]);

    acc[0][0] = __builtin_amdgcn_mfma_f32_16x16x32_f16(ah0, bh0, acc[0][0], 0, 0, 0);
    acc[0][0] = __builtin_amdgcn_mfma_f32_16x16x32_f16(ah0, bl0, acc[0][0], 0, 0, 0);
    acc[0][0] = __builtin_amdgcn_mfma_f32_16x16x32_f16(al0, bh0, acc[0][0], 0, 0, 0);
    acc[0][1] = __builtin_amdgcn_mfma_f32_16x16x32_f16(ah0, bh1, acc[0][1], 0, 0, 0);
    acc[0][1] = __builtin_amdgcn_mfma_f32_16x16x32_f16(ah0, bl1, acc[0][1], 0, 0, 0);
    acc[0][1] = __builtin_amdgcn_mfma_f32_16x16x32_f16(al0, bh1, acc[0][1], 0, 0, 0);
    acc[1][0] = __builtin_amdgcn_mfma_f32_16x16x32_f16(ah1, bh0, acc[1][0], 0, 0, 0);
    acc[1][0] = __builtin_amdgcn_mfma_f32_16x16x32_f16(ah1, bl0, acc[1][0], 0, 0, 0);
    acc[1][0] = __builtin_amdgcn_mfma_f32_16x16x32_f16(al1, bh0, acc[1][0], 0, 0, 0);
    acc[1][1] = __builtin_amdgcn_mfma_f32_16x16x32_f16(ah1, bh1, acc[1][1], 0, 0, 0);
    acc[1][1] = __builtin_amdgcn_mfma_f32_16x16x32_f16(ah1, bl1, acc[1][1], 0, 0, 0);
    acc[1][1] = __builtin_amdgcn_mfma_f32_16x16x32_f16(al1, bh1, acc[1][1], 0, 0, 0);
    __syncthreads();
  }

#pragma unroll
  for (int am = 0; am < 2; am++) {
#pragma unroll
    for (int bn = 0; bn < 2; bn++) {
      int col = n0 + 32 * wn + 16 * bn + lrow;
      float bv = br1[col];
#pragma unroll
      for (int r = 0; r < 4; r++) {
        int rowt = 32 * wm + 16 * am + (lane >> 4) * 4 + r;
        float v = acc[am][bn][r] + bv;
        hrf[(size_t)(m0 + rowt) * H_DIM + col] = fmaxf(v, 0.f);
      }
    }
  }
}

// logits = hrf @ Wr2 + br2 ; one wave per token (fp32)
__global__ __launch_bounds__(256) void router_logits_kernel(
    const float* __restrict__ hrf, const float* __restrict__ Wr2,
    const float* __restrict__ br2, float* __restrict__ logits) {
  int t = blockIdx.x * 4 + (threadIdx.x >> 6);
  int lane = threadIdx.x & 63;
  float acc[E_NUM];
#pragma unroll
  for (int e = 0; e < E_NUM; e++) acc[e] = 0.f;
  const float* hr = hrf + (size_t)t * H_DIM;
#pragma unroll 4
  for (int i = 0; i < H_DIM / 64; i++) {
    int k = lane + 64 * i;
    float a = hr[k];
    const floatx4* w4 = reinterpret_cast<const floatx4*>(Wr2 + (size_t)k * E_NUM);
    floatx4 w0 = w4[0], w1 = w4[1], w2 = w4[2], w3 = w4[3];
#pragma unroll
    for (int j = 0; j < 4; j++) {
      acc[j]      += a * w0[j];
      acc[4 + j]  += a * w1[j];
      acc[8 + j]  += a * w2[j];
      acc[12 + j] += a * w3[j];
    }
  }
#pragma unroll
  for (int e = 0; e < E_NUM; e++) {
    float v = acc[e];
    for (int off = 32; off > 0; off >>= 1) v += __shfl_xor(v, off);
    if (lane == e) logits[(size_t)t * E_NUM + e] = v + br2[e];
  }
}

// per-token top-4 + softmax + counts
__global__ void route_kernel(const float* __restrict__ logits, int* __restrict__ topi,
                             float* __restrict__ topw, int* __restrict__ counts) {
  int t = blockIdx.x * 256 + threadIdx.x;
  if (t >= T_TOK) return;
  float lg[E_NUM];
#pragma unroll
  for (int e = 0; e < E_NUM; e++) lg[e] = logits[(size_t)t * E_NUM + e];
  unsigned int used = 0;
  float vals[K_TOP]; int idx[K_TOP];
#pragma unroll
  for (int k = 0; k < K_TOP; k++) {
    float best = -1e30f; int bi = 0;
#pragma unroll
    for (int e = 0; e < E_NUM; e++) {
      if (!((used >> e) & 1u) && lg[e] > best) { best = lg[e]; bi = e; }
    }
    used |= (1u << bi);
    vals[k] = best; idx[k] = bi;
  }
  float m = vals[0];
  float s = 0.f;
  float w[K_TOP];
#pragma unroll
  for (int k = 0; k < K_TOP; k++) { w[k] = expf(vals[k] - m); s += w[k]; }
  float inv = 1.f / s;
#pragma unroll
  for (int k = 0; k < K_TOP; k++) {
    topi[t * K_TOP + k] = idx[k];
    topw[t * K_TOP + k] = w[k] * inv;
    atomicAdd(&counts[idx[k]], 1);
  }
}

__global__ void scan_kernel(const int* __restrict__ counts, int* __restrict__ offsets,
                            int* __restrict__ cursor) {
  if (threadIdx.x == 0) {
    int acc = 0;
    offsets[0] = 0;
    for (int e = 0; e < E_NUM; e++) { acc += counts[e]; offsets[e + 1] = acc; }
  }
  if (threadIdx.x < E_NUM) cursor[threadIdx.x] = 0;
}

__global__ void scatter_kernel(const int* __restrict__ topi, const float* __restrict__ topw,
                               const int* __restrict__ offsets, int* __restrict__ cursor,
                               int* __restrict__ tok_of_slot, float* __restrict__ w_of_slot,
                               int* __restrict__ slot_of_tk) {
  int t = blockIdx.x * 256 + threadIdx.x;
  if (t >= T_TOK) return;
#pragma unroll
  for (int k = 0; k < K_TOP; k++) {
    int e = topi[t * K_TOP + k];
    int pos = atomicAdd(&cursor[e], 1);
    int slot = offsets[e] + pos;
    tok_of_slot[slot] = t;
    w_of_slot[slot] = topw[t * K_TOP + k];
    slot_of_tk[t * K_TOP + k] = slot;
  }
}

// out[t][h] = sum_k ybuf[slot_of_tk[t][k]][h]
__global__ void combine_kernel(const float* __restrict__ ybuf, const int* __restrict__ slot_of_tk,
                               float* __restrict__ out) {
  int i = blockIdx.x * 256 + threadIdx.x;
  size_t p = (size_t)i * 4;
  int t = (int)(p >> 10);
  int h = (int)(p & 1023);
  float s0 = 0.f, s1 = 0.f, s2 = 0.f, s3 = 0.f;
#pragma unroll
  for (int k = 0; k < K_TOP; k++) {
    int slot = slot_of_tk[t * K_TOP + k];
    const floatx4 v = *reinterpret_cast<const floatx4*>(ybuf + (size_t)slot * H_DIM + h);
    s0 += v[0]; s1 += v[1]; s2 += v[2]; s3 += v[3];
  }
  floatx4 o = {s0, s1, s2, s3};
  *reinterpret_cast<floatx4*>(out + p) = o;
}

// ---------------- MFMA GEMM (fp16 inputs, fp32 weights converted in-flight) ----------------
// ACT: 0 none, 2 exact gelu
template <int ACT, bool GATHER, bool OFFS, bool SCALE, bool OUTF16>
__global__ __launch_bounds__(256) void moe_gemm(
    const _Float16* __restrict__ A, const float* __restrict__ W,
    const float* __restrict__ bias, void* __restrict__ Out,
    const int* __restrict__ offsets, const int* __restrict__ toklist,
    const float* __restrict__ wslot, int M, int N, int K) {
  int e = blockIdx.z;
  int base = 0, cnt = M;
  if (OFFS) { base = offsets[e]; cnt = offsets[e + 1] - base; }
  int m0 = blockIdx.y * 64;
  if (m0 >= cnt) return;
  int n0 = blockIdx.x * 64;
  const float* We = W + (size_t)e * K * N;
  const float* be = bias + (size_t)e * N;

  __shared__ _Float16 As[64][40];
  __shared__ _Float16 Bs[64][40];

  int tid = threadIdx.x;
  int arow = tid >> 2, achk = tid & 3;
  int am_idx = m0 + arow; if (am_idx > cnt - 1) am_idx = cnt - 1;
  long arowg = GATHER ? (long)toklist[base + am_idx] : (long)(base + am_idx);
  const _Float16* Arow = A + arowg * (long)K + achk * 8;

  int brow = tid >> 3, bq = tid & 7;

  floatx4 acc[2][2];
#pragma unroll
  for (int i = 0; i < 2; i++)
#pragma unroll
    for (int j = 0; j < 2; j++) acc[i][j] = (floatx4){0.f, 0.f, 0.f, 0.f};

  int wv = tid >> 6, lane = tid & 63;
  int wm = wv >> 1, wn = wv & 1;
  int lrow = lane & 15, lk = (lane >> 4) * 8;

  for (int k0 = 0; k0 < K; k0 += 32) {
    *reinterpret_cast<f16x8*>(&As[arow][achk * 8]) = *reinterpret_cast<const f16x8*>(Arow + k0);
    const float* wp = We + (size_t)(k0 + brow) * N + n0 + bq * 4;
    floatx4 w0 = *reinterpret_cast<const floatx4*>(wp);
    floatx4 w1 = *reinterpret_cast<const floatx4*>(wp + 32);
#pragma unroll
    for (int i = 0; i < 4; i++) {
      Bs[bq * 4 + i][brow]      = (_Float16)w0[i];
      Bs[32 + bq * 4 + i][brow] = (_Float16)w1[i];
    }
    __syncthreads();

    f16x8 a0 = *reinterpret_cast<const f16x8*>(&As[32 * wm + lrow][lk]);
    f16x8 a1 = *reinterpret_cast<const f16x8*>(&As[32 * wm + 16 + lrow][lk]);
    f16x8 b0 = *reinterpret_cast<const f16x8*>(&Bs[32 * wn + lrow][lk]);
    f16x8 b1 = *reinterpret_cast<const f16x8*>(&Bs[32 * wn + 16 + lrow][lk]);
    acc[0][0] = __builtin_amdgcn_mfma_f32_16x16x32_f16(a0, b0, acc[0][0], 0, 0, 0);
    acc[0][1] = __builtin_amdgcn_mfma_f32_16x16x32_f16(a0, b1, acc[0][1], 0, 0, 0);
    acc[1][0] = __builtin_amdgcn_mfma_f32_16x16x32_f16(a1, b0, acc[1][0], 0, 0, 0);
    acc[1][1] = __builtin_amdgcn_mfma_f32_16x16x32_f16(a1, b1, acc[1][1], 0, 0, 0);
    __syncthreads();
  }

#pragma unroll
  for (int am = 0; am < 2; am++) {
#pragma unroll
    for (int bn = 0; bn < 2; bn++) {
      int col = n0 + 32 * wn + 16 * bn + lrow;
      float bv = be[col];
#pragma unroll
      for (int r = 0; r < 4; r++) {
        int rowt = 32 * wm + 16 * am + (lane >> 4) * 4 + r;
        int mg = m0 + rowt;
        if (mg < cnt) {
          float v = acc[am][bn][r] + bv;
          if (ACT == 2) v = 0.5f * v * (1.f + erff(v * 0.70710678118654752f));
          long orow = base + mg;
          if (SCALE) v *= wslot[orow];
          if (OUTF16)
            ((_Float16*)Out)[orow * (long)N + col] = (_Float16)v;
          else
            ((float*)Out)[orow * (long)N + col] = v;
        }
      }
    }
  }
}

// ---------------- launch ----------------
extern "C" void kernel_launch(void* const* d_in, const int* in_sizes, int n_in,
                              void* d_out, int out_size, void* d_ws, size_t ws_size,
                              hipStream_t stream) {
  const float* x   = (const float*)d_in[0];
  const float* Wr1 = (const float*)d_in[1];
  const float* br1 = (const float*)d_in[2];
  const float* Wr2 = (const float*)d_in[3];
  const float* br2 = (const float*)d_in[4];
  const float* W1  = (const float*)d_in[5];
  const float* b1  = (const float*)d_in[6];
  const float* W2  = (const float*)d_in[7];
  const float* b2  = (const float*)d_in[8];
  float* out = (float*)d_out;

  char* ws = (char*)d_ws;
  _Float16* xh   = (_Float16*)(ws + XH_OFF);
  float*    hrf  = (float*)(ws + HBUF_OFF);      // 8 MB, dead before hbuf is written
  _Float16* hbuf = (_Float16*)(ws + HBUF_OFF);
  float* ybuf   = (float*)(ws + YBUF_OFF);
  float* logits = (float*)(ws + LOGIT_OFF);
  int*   topi   = (int*)(ws + TOPI_OFF);
  float* topw   = (float*)(ws + TOPW_OFF);
  int*   counts = (int*)(ws + CNT_OFF);
  int*   offs   = (int*)(ws + OFFS_OFF);
  int*   cursor = (int*)(ws + CUR_OFF);
  int*   toks   = (int*)(ws + TOKS_OFF);
  float* wsl    = (float*)(ws + WSL_OFF);
  int*   stk    = (int*)(ws + STK_OFF);

  zero_counts_kernel<<<1, 64, 0, stream>>>(counts);
  cast_x_kernel<<<(T_TOK * H_DIM / 8) / 256, 256, 0, stream>>>(x, xh);

  // router GEMM1 (near-fp32): hrf = relu(x @ Wr1 + br1)
  router_gemm1_kernel<<<dim3(H_DIM / 64, T_TOK / 64), 256, 0, stream>>>(x, Wr1, br1, hrf);

  router_logits_kernel<<<T_TOK / 4, 256, 0, stream>>>(hrf, Wr2, br2, logits);
  route_kernel<<<T_TOK / 256, 256, 0, stream>>>(logits, topi, topw, counts);
  scan_kernel<<<1, 64, 0, stream>>>(counts, offs, cursor);
  scatter_kernel<<<T_TOK / 256, 256, 0, stream>>>(topi, topw, offs, cursor, toks, wsl, stk);

  // expert GEMM1: hbuf = gelu(x[tok] @ W1[e] + b1[e]) f16
  moe_gemm<2, true, true, false, true><<<dim3(F_DIM / 64, T_TOK / 64, E_NUM), 256, 0, stream>>>(
      xh, W1, b1, (void*)hbuf, offs, toks, nullptr, T_TOK, F_DIM, H_DIM);

  // expert GEMM2: ybuf = (hbuf @ W2[e] + b2[e]) * w, fp32
  moe_gemm<0, false, true, true, false><<<dim3(H_DIM / 64, T_TOK / 64, E_NUM), 256, 0, stream>>>(
      hbuf, W2, b2, (void*)ybuf, offs, nullptr, wsl, T_TOK, H_DIM, F_DIM);

  combine_kernel<<<(T_TOK * H_DIM / 4) / 256, 256, 0, stream>>>(ybuf, stk, out);
}

// Round 3
// 603.840 us; speedup vs baseline: 1.1313x; 1.1313x over previous
//
#include <hip/hip_runtime.h>
#include <hip/hip_bf16.h>

// ---------------- problem constants ----------------
#define T_TOK 2048
#define H_DIM 1024
#define F_DIM 4096
#define E_NUM 16
#define K_TOP 4

typedef float    floatx4 __attribute__((ext_vector_type(4)));
typedef _Float16 f16x8   __attribute__((ext_vector_type(8)));
typedef _Float16 f16x4   __attribute__((ext_vector_type(4)));

// ---------------- ws layout (bytes) ----------------
#define MiB (1024ull * 1024ull)
#define LOGIT_OFF ((size_t)0)
#define TOPI_OFF  (128ull * 1024)
#define TOPW_OFF  (192ull * 1024)
#define CNT_OFF   (256ull * 1024)
#define OFFS_OFF  (CNT_OFF + 256)
#define CUR_OFF   (OFFS_OFF + 256)
#define TOKS_OFF  (320ull * 1024)
#define WSL_OFF   (384ull * 1024)
#define STK_OFF   (448ull * 1024)
#define XH_OFF    (1ull * MiB)     // 4 MiB f16
#define HBUF_OFF  (8ull * MiB)     // 64 MiB f16 (hrf f32 8 MiB overlays start)
#define YBUF_OFF  (72ull * MiB)    // 32 MiB f32
#define W1T_OFF   (104ull * MiB)   // 128 MiB f16 [E][F][H]
#define W2T_OFF   (232ull * MiB)   // 128 MiB f16 [E][H][F]
#define WS_NEED_FAST (360ull * MiB)

// ---------------- helpers ----------------
__device__ __forceinline__ void gload16(const void* g, void* l) {
  __builtin_amdgcn_global_load_lds(
      (const __attribute__((address_space(1))) unsigned int*)g,
      (__attribute__((address_space(3))) unsigned int*)l, 16, 0, 0);
}

// ---------------- small kernels ----------------
__global__ void zero_counts_kernel(int* counts) {
  if (threadIdx.x < E_NUM) counts[threadIdx.x] = 0;
}

__global__ void cast_x_kernel(const float* __restrict__ x, _Float16* __restrict__ xh) {
  int i = blockIdx.x * 256 + threadIdx.x;       // 8 elems each
  const floatx4* xin = reinterpret_cast<const floatx4*>(x) + (size_t)i * 2;
  floatx4 a = xin[0], b = xin[1];
  f16x8 o;
  o[0] = (_Float16)a[0]; o[1] = (_Float16)a[1]; o[2] = (_Float16)a[2]; o[3] = (_Float16)a[3];
  o[4] = (_Float16)b[0]; o[5] = (_Float16)b[1]; o[6] = (_Float16)b[2]; o[7] = (_Float16)b[3];
  *reinterpret_cast<f16x8*>(xh + (size_t)i * 8) = o;
}

// transpose-cast: W [z][K][N] f32 -> Wt [z][N][K] f16. 64x64 tiles.
__global__ __launch_bounds__(256) void tcast_kernel(const float* __restrict__ W,
                                                    _Float16* __restrict__ Wt, int K, int N) {
  int e = blockIdx.z;
  int k0 = blockIdx.y * 64, n0 = blockIdx.x * 64;
  __shared__ _Float16 Tt[64][64];   // [k][n]
  const float* We = W + (size_t)e * K * N;
  int t = threadIdx.x;
  int kk = t >> 4, nn = (t & 15) * 4;
#pragma unroll
  for (int j = 0; j < 4; j++) {
    int k = kk + 16 * j;
    floatx4 v = *reinterpret_cast<const floatx4*>(We + (size_t)(k0 + k) * N + n0 + nn);
    f16x4 h = {(_Float16)v[0], (_Float16)v[1], (_Float16)v[2], (_Float16)v[3]};
    *reinterpret_cast<f16x4*>(&Tt[k][nn]) = h;
  }
  __syncthreads();
  int n = t & 63, kq = t >> 6;      // 16 k per thread, conflict-free LDS reads
  f16x8 o0, o1;
#pragma unroll
  for (int j = 0; j < 8; j++) { o0[j] = Tt[kq * 16 + j][n]; o1[j] = Tt[kq * 16 + 8 + j][n]; }
  _Float16* dst = Wt + (size_t)e * N * K + (size_t)(n0 + n) * K + k0 + kq * 16;
  *reinterpret_cast<f16x8*>(dst) = o0;
  *reinterpret_cast<f16x8*>(dst + 8) = o1;
}

// ---- router GEMM1, near-fp32 via 3-term fp16 split: hrf = relu(x @ Wr1 + br1), fp32 out ----
__global__ __launch_bounds__(256) void router_gemm1_kernel(
    const float* __restrict__ x, const float* __restrict__ Wr1,
    const float* __restrict__ br1, float* __restrict__ hrf) {
  int m0 = blockIdx.y * 64, n0 = blockIdx.x * 64;
  __shared__ _Float16 Ah[64][40];
  __shared__ _Float16 Al[64][40];
  __shared__ _Float16 Bh[64][40];
  __shared__ _Float16 Bl[64][40];
  int tid = threadIdx.x;
  int arow = tid >> 2, achk = tid & 3;
  const float* Arow = x + (size_t)(m0 + arow) * H_DIM + achk * 8;
  int brow = tid >> 3, bq = tid & 7;

  floatx4 acc[2][2];
#pragma unroll
  for (int i = 0; i < 2; i++)
#pragma unroll
    for (int j = 0; j < 2; j++) acc[i][j] = (floatx4){0.f, 0.f, 0.f, 0.f};

  int wv = tid >> 6, lane = tid & 63;
  int wm = wv >> 1, wn = wv & 1;
  int lrow = lane & 15, lk = (lane >> 4) * 8;

  for (int k0 = 0; k0 < H_DIM; k0 += 32) {
    floatx4 a0 = *reinterpret_cast<const floatx4*>(Arow + k0);
    floatx4 a1 = *reinterpret_cast<const floatx4*>(Arow + k0 + 4);
    f16x8 hv, lv;
#pragma unroll
    for (int j = 0; j < 4; j++) {
      _Float16 hi = (_Float16)a0[j]; hv[j] = hi; lv[j] = (_Float16)(a0[j] - (float)hi);
      _Float16 hi2 = (_Float16)a1[j]; hv[4 + j] = hi2; lv[4 + j] = (_Float16)(a1[j] - (float)hi2);
    }
    *reinterpret_cast<f16x8*>(&Ah[arow][achk * 8]) = hv;
    *reinterpret_cast<f16x8*>(&Al[arow][achk * 8]) = lv;
    const float* wp = Wr1 + (size_t)(k0 + brow) * H_DIM + n0 + bq * 4;
    floatx4 w0 = *reinterpret_cast<const floatx4*>(wp);
    floatx4 w1 = *reinterpret_cast<const floatx4*>(wp + 32);
#pragma unroll
    for (int i = 0; i < 4; i++) {
      _Float16 h0 = (_Float16)w0[i];
      Bh[bq * 4 + i][brow] = h0; Bl[bq * 4 + i][brow] = (_Float16)(w0[i] - (float)h0);
      _Float16 h1 = (_Float16)w1[i];
      Bh[32 + bq * 4 + i][brow] = h1; Bl[32 + bq * 4 + i][brow] = (_Float16)(w1[i] - (float)h1);
    }
    __syncthreads();

    f16x8 ah0 = *reinterpret_cast<const f16x8*>(&Ah[32 * wm + lrow][lk]);
    f16x8 ah1 = *reinterpret_cast<const f16x8*>(&Ah[32 * wm + 16 + lrow][lk]);
    f16x8 al0 = *reinterpret_cast<const f16x8*>(&Al[32 * wm + lrow][lk]);
    f16x8 al1 = *reinterpret_cast<const f16x8*>(&Al[32 * wm + 16 + lrow][lk]);
    f16x8 bh0 = *reinterpret_cast<const f16x8*>(&Bh[32 * wn + lrow][lk]);
    f16x8 bh1 = *reinterpret_cast<const f16x8*>(&Bh[32 * wn + 16 + lrow][lk]);
    f16x8 bl0 = *reinterpret_cast<const f16x8*>(&Bl[32 * wn + lrow][lk]);
    f16x8 bl1 = *reinterpret_cast<const f16x8*>(&Bl[32 * wn + 16 + lrow][lk]);

    acc[0][0] = __builtin_amdgcn_mfma_f32_16x16x32_f16(ah0, bh0, acc[0][0], 0, 0, 0);
    acc[0][0] = __builtin_amdgcn_mfma_f32_16x16x32_f16(ah0, bl0, acc[0][0], 0, 0, 0);
    acc[0][0] = __builtin_amdgcn_mfma_f32_16x16x32_f16(al0, bh0, acc[0][0], 0, 0, 0);
    acc[0][1] = __builtin_amdgcn_mfma_f32_16x16x32_f16(ah0, bh1, acc[0][1], 0, 0, 0);
    acc[0][1] = __builtin_amdgcn_mfma_f32_16x16x32_f16(ah0, bl1, acc[0][1], 0, 0, 0);
    acc[0][1] = __builtin_amdgcn_mfma_f32_16x16x32_f16(al0, bh1, acc[0][1], 0, 0, 0);
    acc[1][0] = __builtin_amdgcn_mfma_f32_16x16x32_f16(ah1, bh0, acc[1][0], 0, 0, 0);
    acc[1][0] = __builtin_amdgcn_mfma_f32_16x16x32_f16(ah1, bl0, acc[1][0], 0, 0, 0);
    acc[1][0] = __builtin_amdgcn_mfma_f32_16x16x32_f16(al1, bh0, acc[1][0], 0, 0, 0);
    acc[1][1] = __builtin_amdgcn_mfma_f32_16x16x32_f16(ah1, bh1, acc[1][1], 0, 0, 0);
    acc[1][1] = __builtin_amdgcn_mfma_f32_16x16x32_f16(ah1, bl1, acc[1][1], 0, 0, 0);
    acc[1][1] = __builtin_amdgcn_mfma_f32_16x16x32_f16(al1, bh1, acc[1][1], 0, 0, 0);
    __syncthreads();
  }

#pragma unroll
  for (int am = 0; am < 2; am++) {
#pragma unroll
    for (int bn = 0; bn < 2; bn++) {
      int col = n0 + 32 * wn + 16 * bn + lrow;
      float bv = br1[col];
#pragma unroll
      for (int r = 0; r < 4; r++) {
        int rowt = 32 * wm + 16 * am + (lane >> 4) * 4 + r;
        float v = acc[am][bn][r] + bv;
        hrf[(size_t)(m0 + rowt) * H_DIM + col] = fmaxf(v, 0.f);
      }
    }
  }
}

// logits = hrf @ Wr2 + br2 ; one wave per token (fp32)
__global__ __launch_bounds__(256) void router_logits_kernel(
    const float* __restrict__ hrf, const float* __restrict__ Wr2,
    const float* __restrict__ br2, float* __restrict__ logits) {
  int t = blockIdx.x * 4 + (threadIdx.x >> 6);
  int lane = threadIdx.x & 63;
  float acc[E_NUM];
#pragma unroll
  for (int e = 0; e < E_NUM; e++) acc[e] = 0.f;
  const float* hr = hrf + (size_t)t * H_DIM;
#pragma unroll 4
  for (int i = 0; i < H_DIM / 64; i++) {
    int k = lane + 64 * i;
    float a = hr[k];
    const floatx4* w4 = reinterpret_cast<const floatx4*>(Wr2 + (size_t)k * E_NUM);
    floatx4 w0 = w4[0], w1 = w4[1], w2 = w4[2], w3 = w4[3];
#pragma unroll
    for (int j = 0; j < 4; j++) {
      acc[j]      += a * w0[j];
      acc[4 + j]  += a * w1[j];
      acc[8 + j]  += a * w2[j];
      acc[12 + j] += a * w3[j];
    }
  }
#pragma unroll
  for (int e = 0; e < E_NUM; e++) {
    float v = acc[e];
    for (int off = 32; off > 0; off >>= 1) v += __shfl_xor(v, off);
    if (lane == e) logits[(size_t)t * E_NUM + e] = v + br2[e];
  }
}

// per-token top-4 + softmax + counts
__global__ void route_kernel(const float* __restrict__ logits, int* __restrict__ topi,
                             float* __restrict__ topw, int* __restrict__ counts) {
  int t = blockIdx.x * 256 + threadIdx.x;
  if (t >= T_TOK) return;
  float lg[E_NUM];
#pragma unroll
  for (int e = 0; e < E_NUM; e++) lg[e] = logits[(size_t)t * E_NUM + e];
  unsigned int used = 0;
  float vals[K_TOP]; int idx[K_TOP];
#pragma unroll
  for (int k = 0; k < K_TOP; k++) {
    float best = -1e30f; int bi = 0;
#pragma unroll
    for (int e = 0; e < E_NUM; e++) {
      if (!((used >> e) & 1u) && lg[e] > best) { best = lg[e]; bi = e; }
    }
    used |= (1u << bi);
    vals[k] = best; idx[k] = bi;
  }
  float m = vals[0];
  float s = 0.f;
  float w[K_TOP];
#pragma unroll
  for (int k = 0; k < K_TOP; k++) { w[k] = expf(vals[k] - m); s += w[k]; }
  float inv = 1.f / s;
#pragma unroll
  for (int k = 0; k < K_TOP; k++) {
    topi[t * K_TOP + k] = idx[k];
    topw[t * K_TOP + k] = w[k] * inv;
    atomicAdd(&counts[idx[k]], 1);
  }
}

__global__ void scan_kernel(const int* __restrict__ counts, int* __restrict__ offsets,
                            int* __restrict__ cursor) {
  if (threadIdx.x == 0) {
    int acc = 0;
    offsets[0] = 0;
    for (int e = 0; e < E_NUM; e++) { acc += counts[e]; offsets[e + 1] = acc; }
  }
  if (threadIdx.x < E_NUM) cursor[threadIdx.x] = 0;
}

__global__ void scatter_kernel(const int* __restrict__ topi, const float* __restrict__ topw,
                               const int* __restrict__ offsets, int* __restrict__ cursor,
                               int* __restrict__ tok_of_slot, float* __restrict__ w_of_slot,
                               int* __restrict__ slot_of_tk) {
  int t = blockIdx.x * 256 + threadIdx.x;
  if (t >= T_TOK) return;
#pragma unroll
  for (int k = 0; k < K_TOP; k++) {
    int e = topi[t * K_TOP + k];
    int pos = atomicAdd(&cursor[e], 1);
    int slot = offsets[e] + pos;
    tok_of_slot[slot] = t;
    w_of_slot[slot] = topw[t * K_TOP + k];
    slot_of_tk[t * K_TOP + k] = slot;
  }
}

// out[t][h] = sum_k ybuf[slot_of_tk[t][k]][h]
__global__ void combine_kernel(const float* __restrict__ ybuf, const int* __restrict__ slot_of_tk,
                               float* __restrict__ out) {
  int i = blockIdx.x * 256 + threadIdx.x;
  size_t p = (size_t)i * 4;
  int t = (int)(p >> 10);
  int h = (int)(p & 1023);
  float s0 = 0.f, s1 = 0.f, s2 = 0.f, s3 = 0.f;
#pragma unroll
  for (int k = 0; k < K_TOP; k++) {
    int slot = slot_of_tk[t * K_TOP + k];
    const floatx4 v = *reinterpret_cast<const floatx4*>(ybuf + (size_t)slot * H_DIM + h);
    s0 += v[0]; s1 += v[1]; s2 += v[2]; s3 += v[3];
  }
  floatx4 o = {s0, s1, s2, s3};
  *reinterpret_cast<floatx4*>(out + p) = o;
}

// ---------------- FAST MFMA GEMM: 128x128 tile, global_load_lds both operands ----------------
// A f16 [*, K]; Bt f16 [E][N][K] (pre-transposed); grid (N/128, 64, E)
template <int ACT, bool GATHER, bool SCALE, bool OUTF16>
__global__ __launch_bounds__(256) void moe_gemm_fast(
    const _Float16* __restrict__ A, const _Float16* __restrict__ Bt,
    const float* __restrict__ bias, void* __restrict__ Out,
    const int* __restrict__ offsets, const int* __restrict__ toklist,
    const float* __restrict__ wslot, int N, int K) {
  int e = blockIdx.z;
  int base = offsets[e], cnt = offsets[e + 1] - base;
  int m0 = blockIdx.y * 128;
  if (m0 >= cnt) return;
  int n0 = blockIdx.x * 128;

  __shared__ _Float16 As[128][32];
  __shared__ _Float16 Bs[128][32];

  int tid = threadIdx.x;
  int w = tid >> 6, lane = tid & 63;
  int wm = w >> 1, wn = w & 1;
  int lrow = lane & 15, lkc = (lane >> 4) * 8;

  // staging rows for this lane (constant over k)
  int ar0 = w * 32 + (lane >> 2);
  int ar1 = ar0 + 16;
  int ach = (lane & 3) * 8;
  int mr0 = m0 + ar0; if (mr0 >= cnt) mr0 = cnt - 1;
  int mr1 = m0 + ar1; if (mr1 >= cnt) mr1 = cnt - 1;
  long sa0 = (long)(GATHER ? toklist[base + mr0] : (base + mr0)) * K + ach;
  long sa1 = (long)(GATHER ? toklist[base + mr1] : (base + mr1)) * K + ach;
  const _Float16* bge = Bt + (size_t)e * N * K;
  long sb0 = (long)(n0 + ar0) * K + ach;
  long sb1 = (long)(n0 + ar1) * K + ach;
  _Float16* lA0 = &As[w * 32][0];
  _Float16* lA1 = &As[w * 32 + 16][0];
  _Float16* lB0 = &Bs[w * 32][0];
  _Float16* lB1 = &Bs[w * 32 + 16][0];

  floatx4 acc[4][4];
#pragma unroll
  for (int i = 0; i < 4; i++)
#pragma unroll
    for (int j = 0; j < 4; j++) acc[i][j] = (floatx4){0.f, 0.f, 0.f, 0.f};

  for (int k0 = 0; k0 < K; k0 += 32) {
    gload16(A + sa0 + k0, lA0);
    gload16(A + sa1 + k0, lA1);
    gload16(bge + sb0 + k0, lB0);
    gload16(bge + sb1 + k0, lB1);
    __syncthreads();

    f16x8 a[4], b[4];
#pragma unroll
    for (int i = 0; i < 4; i++) {
      a[i] = *reinterpret_cast<const f16x8*>(&As[wm * 64 + i * 16 + lrow][lkc]);
      b[i] = *reinterpret_cast<const f16x8*>(&Bs[wn * 64 + i * 16 + lrow][lkc]);
    }
#pragma unroll
    for (int i = 0; i < 4; i++)
#pragma unroll
      for (int j = 0; j < 4; j++)
        acc[i][j] = __builtin_amdgcn_mfma_f32_16x16x32_f16(a[i], b[j], acc[i][j], 0, 0, 0);
    __syncthreads();
  }

  const float* be = bias + (size_t)e * N;
#pragma unroll
  for (int fm = 0; fm < 4; fm++) {
#pragma unroll
    for (int fn = 0; fn < 4; fn++) {
      int col = n0 + wn * 64 + fn * 16 + lrow;
      float bv = be[col];
#pragma unroll
      for (int r = 0; r < 4; r++) {
        int rowt = wm * 64 + fm * 16 + (lane >> 4) * 4 + r;
        int mg = m0 + rowt;
        if (mg < cnt) {
          float v = acc[fm][fn][r] + bv;
          if (ACT == 2) v = 0.5f * v * (1.f + erff(v * 0.70710678118654752f));
          long orow = base + mg;
          if (SCALE) v *= wslot[orow];
          if (OUTF16)
            ((_Float16*)Out)[orow * (long)N + col] = (_Float16)v;
          else
            ((float*)Out)[orow * (long)N + col] = v;
        }
      }
    }
  }
}

// ---------------- FALLBACK MFMA GEMM (round-2, in-flight convert) ----------------
template <int ACT, bool GATHER, bool OFFS, bool SCALE, bool OUTF16>
__global__ __launch_bounds__(256) void moe_gemm(
    const _Float16* __restrict__ A, const float* __restrict__ W,
    const float* __restrict__ bias, void* __restrict__ Out,
    const int* __restrict__ offsets, const int* __restrict__ toklist,
    const float* __restrict__ wslot, int M, int N, int K) {
  int e = blockIdx.z;
  int base = 0, cnt = M;
  if (OFFS) { base = offsets[e]; cnt = offsets[e + 1] - base; }
  int m0 = blockIdx.y * 64;
  if (m0 >= cnt) return;
  int n0 = blockIdx.x * 64;
  const float* We = W + (size_t)e * K * N;
  const float* be = bias + (size_t)e * N;

  __shared__ _Float16 As[64][40];
  __shared__ _Float16 Bs[64][40];

  int tid = threadIdx.x;
  int arow = tid >> 2, achk = tid & 3;
  int am_idx = m0 + arow; if (am_idx > cnt - 1) am_idx = cnt - 1;
  long arowg = GATHER ? (long)toklist[base + am_idx] : (long)(base + am_idx);
  const _Float16* Arow = A + arowg * (long)K + achk * 8;

  int brow = tid >> 3, bq = tid & 7;

  floatx4 acc[2][2];
#pragma unroll
  for (int i = 0; i < 2; i++)
#pragma unroll
    for (int j = 0; j < 2; j++) acc[i][j] = (floatx4){0.f, 0.f, 0.f, 0.f};

  int wv = tid >> 6, lane = tid & 63;
  int wm = wv >> 1, wn = wv & 1;
  int lrow = lane & 15, lk = (lane >> 4) * 8;

  for (int k0 = 0; k0 < K; k0 += 32) {
    *reinterpret_cast<f16x8*>(&As[arow][achk * 8]) = *reinterpret_cast<const f16x8*>(Arow + k0);
    const float* wp = We + (size_t)(k0 + brow) * N + n0 + bq * 4;
    floatx4 w0 = *reinterpret_cast<const floatx4*>(wp);
    floatx4 w1 = *reinterpret_cast<const floatx4*>(wp + 32);
#pragma unroll
    for (int i = 0; i < 4; i++) {
      Bs[bq * 4 + i][brow]      = (_Float16)w0[i];
      Bs[32 + bq * 4 + i][brow] = (_Float16)w1[i];
    }
    __syncthreads();

    f16x8 a0 = *reinterpret_cast<const f16x8*>(&As[32 * wm + lrow][lk]);
    f16x8 a1 = *reinterpret_cast<const f16x8*>(&As[32 * wm + 16 + lrow][lk]);
    f16x8 b0 = *reinterpret_cast<const f16x8*>(&Bs[32 * wn + lrow][lk]);
    f16x8 b1 = *reinterpret_cast<const f16x8*>(&Bs[32 * wn + 16 + lrow][lk]);
    acc[0][0] = __builtin_amdgcn_mfma_f32_16x16x32_f16(a0, b0, acc[0][0], 0, 0, 0);
    acc[0][1] = __builtin_amdgcn_mfma_f32_16x16x32_f16(a0, b1, acc[0][1], 0, 0, 0);
    acc[1][0] = __builtin_amdgcn_mfma_f32_16x16x32_f16(a1, b0, acc[1][0], 0, 0, 0);
    acc[1][1] = __builtin_amdgcn_mfma_f32_16x16x32_f16(a1, b1, acc[1][1], 0, 0, 0);
    __syncthreads();
  }

#pragma unroll
  for (int am = 0; am < 2; am++) {
#pragma unroll
    for (int bn = 0; bn < 2; bn++) {
      int col = n0 + 32 * wn + 16 * bn + lrow;
      float bv = be[col];
#pragma unroll
      for (int r = 0; r < 4; r++) {
        int rowt = 32 * wm + 16 * am + (lane >> 4) * 4 + r;
        int mg = m0 + rowt;
        if (mg < cnt) {
          float v = acc[am][bn][r] + bv;
          if (ACT == 2) v = 0.5f * v * (1.f + erff(v * 0.70710678118654752f));
          long orow = base + mg;
          if (SCALE) v *= wslot[orow];
          if (OUTF16)
            ((_Float16*)Out)[orow * (long)N + col] = (_Float16)v;
          else
            ((float*)Out)[orow * (long)N + col] = v;
        }
      }
    }
  }
}

// ---------------- launch ----------------
extern "C" void kernel_launch(void* const* d_in, const int* in_sizes, int n_in,
                              void* d_out, int out_size, void* d_ws, size_t ws_size,
                              hipStream_t stream) {
  const float* x   = (const float*)d_in[0];
  const float* Wr1 = (const float*)d_in[1];
  const float* br1 = (const float*)d_in[2];
  const float* Wr2 = (const float*)d_in[3];
  const float* br2 = (const float*)d_in[4];
  const float* W1  = (const float*)d_in[5];
  const float* b1  = (const float*)d_in[6];
  const float* W2  = (const float*)d_in[7];
  const float* b2  = (const float*)d_in[8];
  float* out = (float*)d_out;

  char* ws = (char*)d_ws;
  float* logits = (float*)(ws + LOGIT_OFF);
  int*   topi   = (int*)(ws + TOPI_OFF);
  float* topw   = (float*)(ws + TOPW_OFF);
  int*   counts = (int*)(ws + CNT_OFF);
  int*   offs   = (int*)(ws + OFFS_OFF);
  int*   cursor = (int*)(ws + CUR_OFF);
  int*   toks   = (int*)(ws + TOKS_OFF);
  float* wsl    = (float*)(ws + WSL_OFF);
  int*   stk    = (int*)(ws + STK_OFF);
  _Float16* xh   = (_Float16*)(ws + XH_OFF);
  float*    hrf  = (float*)(ws + HBUF_OFF);
  _Float16* hbuf = (_Float16*)(ws + HBUF_OFF);
  float*    ybuf = (float*)(ws + YBUF_OFF);
  _Float16* W1t  = (_Float16*)(ws + W1T_OFF);
  _Float16* W2t  = (_Float16*)(ws + W2T_OFF);

  bool fast = ws_size >= WS_NEED_FAST;

  zero_counts_kernel<<<1, 64, 0, stream>>>(counts);
  cast_x_kernel<<<(T_TOK * H_DIM / 8) / 256, 256, 0, stream>>>(x, xh);

  if (fast) {
    // weight transpose-cast: W1 [E][H][F] -> W1t [E][F][H]; W2 [E][F][H] -> W2t [E][H][F]
    tcast_kernel<<<dim3(F_DIM / 64, H_DIM / 64, E_NUM), 256, 0, stream>>>(W1, W1t, H_DIM, F_DIM);
    tcast_kernel<<<dim3(H_DIM / 64, F_DIM / 64, E_NUM), 256, 0, stream>>>(W2, W2t, F_DIM, H_DIM);
  }

  router_gemm1_kernel<<<dim3(H_DIM / 64, T_TOK / 64), 256, 0, stream>>>(x, Wr1, br1, hrf);
  router_logits_kernel<<<T_TOK / 4, 256, 0, stream>>>(hrf, Wr2, br2, logits);
  route_kernel<<<T_TOK / 256, 256, 0, stream>>>(logits, topi, topw, counts);
  scan_kernel<<<1, 64, 0, stream>>>(counts, offs, cursor);
  scatter_kernel<<<T_TOK / 256, 256, 0, stream>>>(topi, topw, offs, cursor, toks, wsl, stk);

  if (fast) {
    moe_gemm_fast<2, true, false, true><<<dim3(F_DIM / 128, 64, E_NUM), 256, 0, stream>>>(
        xh, W1t, b1, (void*)hbuf, offs, toks, nullptr, F_DIM, H_DIM);
    moe_gemm_fast<0, false, true, false><<<dim3(H_DIM / 128, 64, E_NUM), 256, 0, stream>>>(
        hbuf, W2t, b2, (void*)ybuf, offs, nullptr, wsl, H_DIM, F_DIM);
  } else {
    moe_gemm<2, true, true, false, true><<<dim3(F_DIM / 64, T_TOK / 64, E_NUM), 256, 0, stream>>>(
        xh, W1, b1, (void*)hbuf, offs, toks, nullptr, T_TOK, F_DIM, H_DIM);
    moe_gemm<0, false, true, true, false><<<dim3(H_DIM / 64, T_TOK / 64, E_NUM), 256, 0, stream>>>(
        hbuf, W2, b2, (void*)ybuf, offs, nullptr, wsl, T_TOK, H_DIM, F_DIM);
  }

  combine_kernel<<<(T_TOK * H_DIM / 4) / 256, 256, 0, stream>>>(ybuf, stk, out);
}

// Round 4
// 569.759 us; speedup vs baseline: 1.1990x; 1.0598x over previous
//
#include <hip/hip_runtime.h>
#include <hip/hip_bf16.h>

// ---------------- problem constants ----------------
#define T_TOK 2048
#define H_DIM 1024
#define F_DIM 4096
#define E_NUM 16
#define K_TOP 4

typedef float    floatx4 __attribute__((ext_vector_type(4)));
typedef _Float16 f16x8   __attribute__((ext_vector_type(8)));
typedef _Float16 f16x4   __attribute__((ext_vector_type(4)));

// ---------------- ws layout (bytes) ----------------
#define MiB (1024ull * 1024ull)
#define LOGIT_OFF ((size_t)0)
#define TOPI_OFF  (128ull * 1024)
#define TOPW_OFF  (192ull * 1024)
#define CNT_OFF   (256ull * 1024)
#define OFFS_OFF  (CNT_OFF + 256)
#define CUR_OFF   (OFFS_OFF + 256)
#define TOKS_OFF  (320ull * 1024)
#define WSL_OFF   (384ull * 1024)
#define STK_OFF   (448ull * 1024)
#define TILEE_OFF (512ull * 1024)
#define TILEM_OFF (TILEE_OFF + 512)
#define TILEC_OFF (TILEM_OFF + 512)
#define XH_OFF    (1ull * MiB)     // 4 MiB f16
#define HBUF_OFF  (8ull * MiB)     // 64 MiB f16 (hrf f32 8 MiB overlays start)
#define YBUF_OFF  (72ull * MiB)    // 32 MiB f32
#define W1T_OFF   (104ull * MiB)   // 128 MiB f16 [E][F][H]
#define W2T_OFF   (232ull * MiB)   // 128 MiB f16 [E][H][F]
#define WS_NEED_FAST (360ull * MiB)

// ---------------- helpers ----------------
__device__ __forceinline__ void gload16(const void* g, void* l) {
  __builtin_amdgcn_global_load_lds(
      (const __attribute__((address_space(1))) unsigned int*)g,
      (__attribute__((address_space(3))) unsigned int*)l, 16, 0, 0);
}

// ---------------- small kernels ----------------
__global__ void zero_counts_kernel(int* counts) {
  if (threadIdx.x < E_NUM) counts[threadIdx.x] = 0;
}

__global__ void cast_x_kernel(const float* __restrict__ x, _Float16* __restrict__ xh) {
  int i = blockIdx.x * 256 + threadIdx.x;       // 8 elems each
  const floatx4* xin = reinterpret_cast<const floatx4*>(x) + (size_t)i * 2;
  floatx4 a = xin[0], b = xin[1];
  f16x8 o;
  o[0] = (_Float16)a[0]; o[1] = (_Float16)a[1]; o[2] = (_Float16)a[2]; o[3] = (_Float16)a[3];
  o[4] = (_Float16)b[0]; o[5] = (_Float16)b[1]; o[6] = (_Float16)b[2]; o[7] = (_Float16)b[3];
  *reinterpret_cast<f16x8*>(xh + (size_t)i * 8) = o;
}

// transpose-cast: W [z][K][N] f32 -> Wt [z][N][K] f16. 64x64 tiles.
// Coalesced loads (4 full lines/instr) AND stores (16 full 128B lines/instr).
__global__ __launch_bounds__(256) void tcast_kernel(const float* __restrict__ W,
                                                    _Float16* __restrict__ Wt, int K, int N) {
  int e = blockIdx.z;
  int k0 = blockIdx.y * 64, n0 = blockIdx.x * 64;
  __shared__ float Tt[64][68];   // [k][n], pad 68: store 2-way free, read 4-way (benign)
  const float* We = W + (size_t)e * K * N;
  int t = threadIdx.x;
  int kk = t >> 4, nn = (t & 15) * 4;
#pragma unroll
  for (int j = 0; j < 4; j++) {
    int k = kk + 16 * j;
    floatx4 v = *reinterpret_cast<const floatx4*>(We + (size_t)(k0 + k) * N + n0 + nn);
    *reinterpret_cast<floatx4*>(&Tt[k][nn]) = v;
  }
  __syncthreads();
  int nr = t >> 2, kc = t & 3;   // out row nr (0..63), k-chunk kc (16 k each)
  f16x8 o0, o1;
#pragma unroll
  for (int j = 0; j < 8; j++) {
    o0[j] = (_Float16)Tt[kc * 16 + j][nr];
    o1[j] = (_Float16)Tt[kc * 16 + 8 + j][nr];
  }
  _Float16* dst = Wt + (size_t)e * N * K + (size_t)(n0 + nr) * K + k0 + kc * 16;
  *reinterpret_cast<f16x8*>(dst) = o0;
  *reinterpret_cast<f16x8*>(dst + 8) = o1;
}

// ---- router GEMM1, near-fp32 via 3-term fp16 split: hrf = relu(x @ Wr1 + br1), fp32 out ----
__global__ __launch_bounds__(256) void router_gemm1_kernel(
    const float* __restrict__ x, const float* __restrict__ Wr1,
    const float* __restrict__ br1, float* __restrict__ hrf) {
  int m0 = blockIdx.y * 64, n0 = blockIdx.x * 64;
  __shared__ _Float16 Ah[64][40];
  __shared__ _Float16 Al[64][40];
  __shared__ _Float16 Bh[64][40];
  __shared__ _Float16 Bl[64][40];
  int tid = threadIdx.x;
  int arow = tid >> 2, achk = tid & 3;
  const float* Arow = x + (size_t)(m0 + arow) * H_DIM + achk * 8;
  int brow = tid >> 3, bq = tid & 7;

  floatx4 acc[2][2];
#pragma unroll
  for (int i = 0; i < 2; i++)
#pragma unroll
    for (int j = 0; j < 2; j++) acc[i][j] = (floatx4){0.f, 0.f, 0.f, 0.f};

  int wv = tid >> 6, lane = tid & 63;
  int wm = wv >> 1, wn = wv & 1;
  int lrow = lane & 15, lk = (lane >> 4) * 8;

  for (int k0 = 0; k0 < H_DIM; k0 += 32) {
    floatx4 a0 = *reinterpret_cast<const floatx4*>(Arow + k0);
    floatx4 a1 = *reinterpret_cast<const floatx4*>(Arow + k0 + 4);
    f16x8 hv, lv;
#pragma unroll
    for (int j = 0; j < 4; j++) {
      _Float16 hi = (_Float16)a0[j]; hv[j] = hi; lv[j] = (_Float16)(a0[j] - (float)hi);
      _Float16 hi2 = (_Float16)a1[j]; hv[4 + j] = hi2; lv[4 + j] = (_Float16)(a1[j] - (float)hi2);
    }
    *reinterpret_cast<f16x8*>(&Ah[arow][achk * 8]) = hv;
    *reinterpret_cast<f16x8*>(&Al[arow][achk * 8]) = lv;
    const float* wp = Wr1 + (size_t)(k0 + brow) * H_DIM + n0 + bq * 4;
    floatx4 w0 = *reinterpret_cast<const floatx4*>(wp);
    floatx4 w1 = *reinterpret_cast<const floatx4*>(wp + 32);
#pragma unroll
    for (int i = 0; i < 4; i++) {
      _Float16 h0 = (_Float16)w0[i];
      Bh[bq * 4 + i][brow] = h0; Bl[bq * 4 + i][brow] = (_Float16)(w0[i] - (float)h0);
      _Float16 h1 = (_Float16)w1[i];
      Bh[32 + bq * 4 + i][brow] = h1; Bl[32 + bq * 4 + i][brow] = (_Float16)(w1[i] - (float)h1);
    }
    __syncthreads();

    f16x8 ah0 = *reinterpret_cast<const f16x8*>(&Ah[32 * wm + lrow][lk]);
    f16x8 ah1 = *reinterpret_cast<const f16x8*>(&Ah[32 * wm + 16 + lrow][lk]);
    f16x8 al0 = *reinterpret_cast<const f16x8*>(&Al[32 * wm + lrow][lk]);
    f16x8 al1 = *reinterpret_cast<const f16x8*>(&Al[32 * wm + 16 + lrow][lk]);
    f16x8 bh0 = *reinterpret_cast<const f16x8*>(&Bh[32 * wn + lrow][lk]);
    f16x8 bh1 = *reinterpret_cast<const f16x8*>(&Bh[32 * wn + 16 + lrow][lk]);
    f16x8 bl0 = *reinterpret_cast<const f16x8*>(&Bl[32 * wn + lrow][lk]);
    f16x8 bl1 = *reinterpret_cast<const f16x8*>(&Bl[32 * wn + 16 + lrow][lk]);

    acc[0][0] = __builtin_amdgcn_mfma_f32_16x16x32_f16(ah0, bh0, acc[0][0], 0, 0, 0);
    acc[0][0] = __builtin_amdgcn_mfma_f32_16x16x32_f16(ah0, bl0, acc[0][0], 0, 0, 0);
    acc[0][0] = __builtin_amdgcn_mfma_f32_16x16x32_f16(al0, bh0, acc[0][0], 0, 0, 0);
    acc[0][1] = __builtin_amdgcn_mfma_f32_16x16x32_f16(ah0, bh1, acc[0][1], 0, 0, 0);
    acc[0][1] = __builtin_amdgcn_mfma_f32_16x16x32_f16(ah0, bl1, acc[0][1], 0, 0, 0);
    acc[0][1] = __builtin_amdgcn_mfma_f32_16x16x32_f16(al0, bh1, acc[0][1], 0, 0, 0);
    acc[1][0] = __builtin_amdgcn_mfma_f32_16x16x32_f16(ah1, bh0, acc[1][0], 0, 0, 0);
    acc[1][0] = __builtin_amdgcn_mfma_f32_16x16x32_f16(ah1, bl0, acc[1][0], 0, 0, 0);
    acc[1][0] = __builtin_amdgcn_mfma_f32_16x16x32_f16(al1, bh0, acc[1][0], 0, 0, 0);
    acc[1][1] = __builtin_amdgcn_mfma_f32_16x16x32_f16(ah1, bh1, acc[1][1], 0, 0, 0);
    acc[1][1] = __builtin_amdgcn_mfma_f32_16x16x32_f16(ah1, bl1, acc[1][1], 0, 0, 0);
    acc[1][1] = __builtin_amdgcn_mfma_f32_16x16x32_f16(al1, bh1, acc[1][1], 0, 0, 0);
    __syncthreads();
  }

#pragma unroll
  for (int am = 0; am < 2; am++) {
#pragma unroll
    for (int bn = 0; bn < 2; bn++) {
      int col = n0 + 32 * wn + 16 * bn + lrow;
      float bv = br1[col];
#pragma unroll
      for (int r = 0; r < 4; r++) {
        int rowt = 32 * wm + 16 * am + (lane >> 4) * 4 + r;
        float v = acc[am][bn][r] + bv;
        hrf[(size_t)(m0 + rowt) * H_DIM + col] = fmaxf(v, 0.f);
      }
    }
  }
}

// logits = hrf @ Wr2 + br2 ; one wave per token (fp32)
__global__ __launch_bounds__(256) void router_logits_kernel(
    const float* __restrict__ hrf, const float* __restrict__ Wr2,
    const float* __restrict__ br2, float* __restrict__ logits) {
  int t = blockIdx.x * 4 + (threadIdx.x >> 6);
  int lane = threadIdx.x & 63;
  float acc[E_NUM];
#pragma unroll
  for (int e = 0; e < E_NUM; e++) acc[e] = 0.f;
  const float* hr = hrf + (size_t)t * H_DIM;
#pragma unroll 4
  for (int i = 0; i < H_DIM / 64; i++) {
    int k = lane + 64 * i;
    float a = hr[k];
    const floatx4* w4 = reinterpret_cast<const floatx4*>(Wr2 + (size_t)k * E_NUM);
    floatx4 w0 = w4[0], w1 = w4[1], w2 = w4[2], w3 = w4[3];
#pragma unroll
    for (int j = 0; j < 4; j++) {
      acc[j]      += a * w0[j];
      acc[4 + j]  += a * w1[j];
      acc[8 + j]  += a * w2[j];
      acc[12 + j] += a * w3[j];
    }
  }
#pragma unroll
  for (int e = 0; e < E_NUM; e++) {
    float v = acc[e];
    for (int off = 32; off > 0; off >>= 1) v += __shfl_xor(v, off);
    if (lane == e) logits[(size_t)t * E_NUM + e] = v + br2[e];
  }
}

// per-token top-4 + softmax + counts
__global__ void route_kernel(const float* __restrict__ logits, int* __restrict__ topi,
                             float* __restrict__ topw, int* __restrict__ counts) {
  int t = blockIdx.x * 256 + threadIdx.x;
  if (t >= T_TOK) return;
  float lg[E_NUM];
#pragma unroll
  for (int e = 0; e < E_NUM; e++) lg[e] = logits[(size_t)t * E_NUM + e];
  unsigned int used = 0;
  float vals[K_TOP]; int idx[K_TOP];
#pragma unroll
  for (int k = 0; k < K_TOP; k++) {
    float best = -1e30f; int bi = 0;
#pragma unroll
    for (int e = 0; e < E_NUM; e++) {
      if (!((used >> e) & 1u) && lg[e] > best) { best = lg[e]; bi = e; }
    }
    used |= (1u << bi);
    vals[k] = best; idx[k] = bi;
  }
  float m = vals[0];
  float s = 0.f;
  float w[K_TOP];
#pragma unroll
  for (int k = 0; k < K_TOP; k++) { w[k] = expf(vals[k] - m); s += w[k]; }
  float inv = 1.f / s;
#pragma unroll
  for (int k = 0; k < K_TOP; k++) {
    topi[t * K_TOP + k] = idx[k];
    topw[t * K_TOP + k] = w[k] * inv;
    atomicAdd(&counts[idx[k]], 1);
  }
}

// prefix scan + compacted m-tile table (shared by both expert GEMMs)
__global__ void scan_kernel(const int* __restrict__ counts, int* __restrict__ offsets,
                            int* __restrict__ cursor, int* __restrict__ tileE,
                            int* __restrict__ tileM, int* __restrict__ tileC) {
  if (threadIdx.x == 0) {
    int acc = 0;
    offsets[0] = 0;
    for (int e = 0; e < E_NUM; e++) { acc += counts[e]; offsets[e + 1] = acc; }
    int idx = 0;
    for (int e = 0; e < E_NUM; e++) {
      int c = counts[e];
      for (int m0 = 0; m0 < c; m0 += 128) { tileE[idx] = e; tileM[idx] = m0; idx++; }
    }
    tileC[0] = idx;   // <= 79
  }
  if (threadIdx.x < E_NUM) cursor[threadIdx.x] = 0;
}

__global__ void scatter_kernel(const int* __restrict__ topi, const float* __restrict__ topw,
                               const int* __restrict__ offsets, int* __restrict__ cursor,
                               int* __restrict__ tok_of_slot, float* __restrict__ w_of_slot,
                               int* __restrict__ slot_of_tk) {
  int t = blockIdx.x * 256 + threadIdx.x;
  if (t >= T_TOK) return;
#pragma unroll
  for (int k = 0; k < K_TOP; k++) {
    int e = topi[t * K_TOP + k];
    int pos = atomicAdd(&cursor[e], 1);
    int slot = offsets[e] + pos;
    tok_of_slot[slot] = t;
    w_of_slot[slot] = topw[t * K_TOP + k];
    slot_of_tk[t * K_TOP + k] = slot;
  }
}

// out[t][h] = sum_k ybuf[slot_of_tk[t][k]][h]
__global__ void combine_kernel(const float* __restrict__ ybuf, const int* __restrict__ slot_of_tk,
                               float* __restrict__ out) {
  int i = blockIdx.x * 256 + threadIdx.x;
  size_t p = (size_t)i * 4;
  int t = (int)(p >> 10);
  int h = (int)(p & 1023);
  float s0 = 0.f, s1 = 0.f, s2 = 0.f, s3 = 0.f;
#pragma unroll
  for (int k = 0; k < K_TOP; k++) {
    int slot = slot_of_tk[t * K_TOP + k];
    const floatx4 v = *reinterpret_cast<const floatx4*>(ybuf + (size_t)slot * H_DIM + h);
    s0 += v[0]; s1 += v[1]; s2 += v[2]; s3 += v[3];
  }
  floatx4 o = {s0, s1, s2, s3};
  *reinterpret_cast<floatx4*>(out + p) = o;
}

// ---------------- FAST MFMA GEMM v2: 128x128 tile, 2-phase dbuf prefetch, tile table ----------
// A f16 [*, K]; Bt f16 [E][N][K]; grid (N/128, 80)
template <int ACT, bool GATHER, bool SCALE, bool OUTF16>
__global__ __launch_bounds__(256) void moe_gemm_fast2(
    const _Float16* __restrict__ A, const _Float16* __restrict__ Bt,
    const float* __restrict__ bias, void* __restrict__ Out,
    const int* __restrict__ offsets, const int* __restrict__ toklist,
    const float* __restrict__ wslot, const int* __restrict__ tileE,
    const int* __restrict__ tileM, const int* __restrict__ tileC,
    int N, int K) {
  int ti = blockIdx.y;
  if (ti >= tileC[0]) return;
  int e = tileE[ti], m0 = tileM[ti];
  int base = offsets[e], cnt = offsets[e + 1] - base;
  int n0 = blockIdx.x * 128;

  __shared__ _Float16 As[2][128][32];
  __shared__ _Float16 Bs[2][128][32];

  int tid = threadIdx.x;
  int w = tid >> 6, lane = tid & 63;
  int wm = w >> 1, wn = w & 1;
  int lrow = lane & 15, lkc = (lane >> 4) * 8;

  // staging: lane -> (row = base + lane>>2, 16B chunk = (lane&3)*8 f16); dest wave-uniform
  int ar0 = w * 32 + (lane >> 2);
  int ar1 = ar0 + 16;
  int ach = (lane & 3) * 8;
  int mr0 = m0 + ar0; if (mr0 >= cnt) mr0 = cnt - 1;
  int mr1 = m0 + ar1; if (mr1 >= cnt) mr1 = cnt - 1;
  const _Float16* gA0 = A + (long)(GATHER ? toklist[base + mr0] : (base + mr0)) * K + ach;
  const _Float16* gA1 = A + (long)(GATHER ? toklist[base + mr1] : (base + mr1)) * K + ach;
  const _Float16* bge = Bt + (size_t)e * N * K;
  const _Float16* gB0 = bge + (long)(n0 + ar0) * K + ach;
  const _Float16* gB1 = bge + (long)(n0 + ar1) * K + ach;

#define STAGE2(buf, kk) do { \
    gload16(gA0 + (kk), &As[buf][w * 32][0]); \
    gload16(gA1 + (kk), &As[buf][w * 32 + 16][0]); \
    gload16(gB0 + (kk), &Bs[buf][w * 32][0]); \
    gload16(gB1 + (kk), &Bs[buf][w * 32 + 16][0]); \
  } while (0)

  floatx4 acc[4][4];
#pragma unroll
  for (int i = 0; i < 4; i++)
#pragma unroll
    for (int j = 0; j < 4; j++) acc[i][j] = (floatx4){0.f, 0.f, 0.f, 0.f};

  STAGE2(0, 0);
  __syncthreads();

  int nk = K >> 5;
  for (int it = 0; it < nk; ++it) {
    int cur = it & 1;
    if (it + 1 < nk) STAGE2(cur ^ 1, (it + 1) << 5);   // prefetch next k-tile

    f16x8 a[4], b[4];
#pragma unroll
    for (int i = 0; i < 4; i++) {
      a[i] = *reinterpret_cast<const f16x8*>(&As[cur][wm * 64 + i * 16 + lrow][lkc]);
      b[i] = *reinterpret_cast<const f16x8*>(&Bs[cur][wn * 64 + i * 16 + lrow][lkc]);
    }
#pragma unroll
    for (int i = 0; i < 4; i++)
#pragma unroll
      for (int j = 0; j < 4; j++)
        acc[i][j] = __builtin_amdgcn_mfma_f32_16x16x32_f16(a[i], b[j], acc[i][j], 0, 0, 0);

    __syncthreads();   // drains prefetch (vmcnt) + all reads of As[cur] before overwrite
  }
#undef STAGE2

  const float* be = bias + (size_t)e * N;
#pragma unroll
  for (int fm = 0; fm < 4; fm++) {
#pragma unroll
    for (int fn = 0; fn < 4; fn++) {
      int col = n0 + wn * 64 + fn * 16 + lrow;
      float bv = be[col];
#pragma unroll
      for (int r = 0; r < 4; r++) {
        int rowt = wm * 64 + fm * 16 + (lane >> 4) * 4 + r;
        int mg = m0 + rowt;
        if (mg < cnt) {
          float v = acc[fm][fn][r] + bv;
          if (ACT == 2) v = 0.5f * v * (1.f + erff(v * 0.70710678118654752f));
          long orow = base + mg;
          if (SCALE) v *= wslot[orow];
          if (OUTF16)
            ((_Float16*)Out)[orow * (long)N + col] = (_Float16)v;
          else
            ((float*)Out)[orow * (long)N + col] = v;
        }
      }
    }
  }
}

// ---------------- FALLBACK MFMA GEMM (in-flight convert, small ws) ----------------
template <int ACT, bool GATHER, bool OFFS, bool SCALE, bool OUTF16>
__global__ __launch_bounds__(256) void moe_gemm(
    const _Float16* __restrict__ A, const float* __restrict__ W,
    const float* __restrict__ bias, void* __restrict__ Out,
    const int* __restrict__ offsets, const int* __restrict__ toklist,
    const float* __restrict__ wslot, int M, int N, int K) {
  int e = blockIdx.z;
  int base = 0, cnt = M;
  if (OFFS) { base = offsets[e]; cnt = offsets[e + 1] - base; }
  int m0 = blockIdx.y * 64;
  if (m0 >= cnt) return;
  int n0 = blockIdx.x * 64;
  const float* We = W + (size_t)e * K * N;
  const float* be = bias + (size_t)e * N;

  __shared__ _Float16 As[64][40];
  __shared__ _Float16 Bs[64][40];

  int tid = threadIdx.x;
  int arow = tid >> 2, achk = tid & 3;
  int am_idx = m0 + arow; if (am_idx > cnt - 1) am_idx = cnt - 1;
  long arowg = GATHER ? (long)toklist[base + am_idx] : (long)(base + am_idx);
  const _Float16* Arow = A + arowg * (long)K + achk * 8;

  int brow = tid >> 3, bq = tid & 7;

  floatx4 acc[2][2];
#pragma unroll
  for (int i = 0; i < 2; i++)
#pragma unroll
    for (int j = 0; j < 2; j++) acc[i][j] = (floatx4){0.f, 0.f, 0.f, 0.f};

  int wv = tid >> 6, lane = tid & 63;
  int wm = wv >> 1, wn = wv & 1;
  int lrow = lane & 15, lk = (lane >> 4) * 8;

  for (int k0 = 0; k0 < K; k0 += 32) {
    *reinterpret_cast<f16x8*>(&As[arow][achk * 8]) = *reinterpret_cast<const f16x8*>(Arow + k0);
    const float* wp = We + (size_t)(k0 + brow) * N + n0 + bq * 4;
    floatx4 w0 = *reinterpret_cast<const floatx4*>(wp);
    floatx4 w1 = *reinterpret_cast<const floatx4*>(wp + 32);
#pragma unroll
    for (int i = 0; i < 4; i++) {
      Bs[bq * 4 + i][brow]      = (_Float16)w0[i];
      Bs[32 + bq * 4 + i][brow] = (_Float16)w1[i];
    }
    __syncthreads();

    f16x8 a0 = *reinterpret_cast<const f16x8*>(&As[32 * wm + lrow][lk]);
    f16x8 a1 = *reinterpret_cast<const f16x8*>(&As[32 * wm + 16 + lrow][lk]);
    f16x8 b0 = *reinterpret_cast<const f16x8*>(&Bs[32 * wn + lrow][lk]);
    f16x8 b1 = *reinterpret_cast<const f16x8*>(&Bs[32 * wn + 16 + lrow][lk]);
    acc[0][0] = __builtin_amdgcn_mfma_f32_16x16x32_f16(a0, b0, acc[0][0], 0, 0, 0);
    acc[0][1] = __builtin_amdgcn_mfma_f32_16x16x32_f16(a0, b1, acc[0][1], 0, 0, 0);
    acc[1][0] = __builtin_amdgcn_mfma_f32_16x16x32_f16(a1, b0, acc[1][0], 0, 0, 0);
    acc[1][1] = __builtin_amdgcn_mfma_f32_16x16x32_f16(a1, b1, acc[1][1], 0, 0, 0);
    __syncthreads();
  }

#pragma unroll
  for (int am = 0; am < 2; am++) {
#pragma unroll
    for (int bn = 0; bn < 2; bn++) {
      int col = n0 + 32 * wn + 16 * bn + lrow;
      float bv = be[col];
#pragma unroll
      for (int r = 0; r < 4; r++) {
        int rowt = 32 * wm + 16 * am + (lane >> 4) * 4 + r;
        int mg = m0 + rowt;
        if (mg < cnt) {
          float v = acc[am][bn][r] + bv;
          if (ACT == 2) v = 0.5f * v * (1.f + erff(v * 0.70710678118654752f));
          long orow = base + mg;
          if (SCALE) v *= wslot[orow];
          if (OUTF16)
            ((_Float16*)Out)[orow * (long)N + col] = (_Float16)v;
          else
            ((float*)Out)[orow * (long)N + col] = v;
        }
      }
    }
  }
}

// ---------------- launch ----------------
extern "C" void kernel_launch(void* const* d_in, const int* in_sizes, int n_in,
                              void* d_out, int out_size, void* d_ws, size_t ws_size,
                              hipStream_t stream) {
  const float* x   = (const float*)d_in[0];
  const float* Wr1 = (const float*)d_in[1];
  const float* br1 = (const float*)d_in[2];
  const float* Wr2 = (const float*)d_in[3];
  const float* br2 = (const float*)d_in[4];
  const float* W1  = (const float*)d_in[5];
  const float* b1  = (const float*)d_in[6];
  const float* W2  = (const float*)d_in[7];
  const float* b2  = (const float*)d_in[8];
  float* out = (float*)d_out;

  char* ws = (char*)d_ws;
  float* logits = (float*)(ws + LOGIT_OFF);
  int*   topi   = (int*)(ws + TOPI_OFF);
  float* topw   = (float*)(ws + TOPW_OFF);
  int*   counts = (int*)(ws + CNT_OFF);
  int*   offs   = (int*)(ws + OFFS_OFF);
  int*   cursor = (int*)(ws + CUR_OFF);
  int*   toks   = (int*)(ws + TOKS_OFF);
  float* wsl    = (float*)(ws + WSL_OFF);
  int*   stk    = (int*)(ws + STK_OFF);
  int*   tileE  = (int*)(ws + TILEE_OFF);
  int*   tileM  = (int*)(ws + TILEM_OFF);
  int*   tileC  = (int*)(ws + TILEC_OFF);
  _Float16* xh   = (_Float16*)(ws + XH_OFF);
  float*    hrf  = (float*)(ws + HBUF_OFF);
  _Float16* hbuf = (_Float16*)(ws + HBUF_OFF);
  float*    ybuf = (float*)(ws + YBUF_OFF);
  _Float16* W1t  = (_Float16*)(ws + W1T_OFF);
  _Float16* W2t  = (_Float16*)(ws + W2T_OFF);

  bool fast = ws_size >= WS_NEED_FAST;

  zero_counts_kernel<<<1, 64, 0, stream>>>(counts);
  cast_x_kernel<<<(T_TOK * H_DIM / 8) / 256, 256, 0, stream>>>(x, xh);

  if (fast) {
    tcast_kernel<<<dim3(F_DIM / 64, H_DIM / 64, E_NUM), 256, 0, stream>>>(W1, W1t, H_DIM, F_DIM);
    tcast_kernel<<<dim3(H_DIM / 64, F_DIM / 64, E_NUM), 256, 0, stream>>>(W2, W2t, F_DIM, H_DIM);
  }

  router_gemm1_kernel<<<dim3(H_DIM / 64, T_TOK / 64), 256, 0, stream>>>(x, Wr1, br1, hrf);
  router_logits_kernel<<<T_TOK / 4, 256, 0, stream>>>(hrf, Wr2, br2, logits);
  route_kernel<<<T_TOK / 256, 256, 0, stream>>>(logits, topi, topw, counts);
  scan_kernel<<<1, 64, 0, stream>>>(counts, offs, cursor, tileE, tileM, tileC);
  scatter_kernel<<<T_TOK / 256, 256, 0, stream>>>(topi, topw, offs, cursor, toks, wsl, stk);

  if (fast) {
    moe_gemm_fast2<2, true, false, true><<<dim3(F_DIM / 128, 80), 256, 0, stream>>>(
        xh, W1t, b1, (void*)hbuf, offs, toks, nullptr, tileE, tileM, tileC, F_DIM, H_DIM);
    moe_gemm_fast2<0, false, true, false><<<dim3(H_DIM / 128, 80), 256, 0, stream>>>(
        hbuf, W2t, b2, (void*)ybuf, offs, nullptr, wsl, tileE, tileM, tileC, H_DIM, F_DIM);
  } else {
    moe_gemm<2, true, true, false, true><<<dim3(F_DIM / 64, T_TOK / 64, E_NUM), 256, 0, stream>>>(
        xh, W1, b1, (void*)hbuf, offs, toks, nullptr, T_TOK, F_DIM, H_DIM);
    moe_gemm<0, false, true, true, false><<<dim3(H_DIM / 64, T_TOK / 64, E_NUM), 256, 0, stream>>>(
        hbuf, W2, b2, (void*)ybuf, offs, nullptr, wsl, T_TOK, H_DIM, F_DIM);
  }

  combine_kernel<<<(T_TOK * H_DIM / 4) / 256, 256, 0, stream>>>(ybuf, stk, out);
}

// Round 5
// 496.105 us; speedup vs baseline: 1.3770x; 1.1485x over previous
//
#include <hip/hip_runtime.h>
#include <hip/hip_bf16.h>

// ---------------- problem constants ----------------
#define T_TOK 2048
#define H_DIM 1024
#define F_DIM 4096
#define E_NUM 16
#define K_TOP 4

typedef float    floatx4 __attribute__((ext_vector_type(4)));
typedef _Float16 f16x8   __attribute__((ext_vector_type(8)));
typedef _Float16 f16x4   __attribute__((ext_vector_type(4)));

// ---------------- ws layout (bytes) ----------------
#define MiB (1024ull * 1024ull)
#define LOGIT_OFF ((size_t)0)
#define TOPI_OFF  (128ull * 1024)
#define TOPW_OFF  (192ull * 1024)
#define CNT_OFF   (256ull * 1024)
#define OFFS_OFF  (CNT_OFF + 256)
#define CUR_OFF   (OFFS_OFF + 256)
#define TOKS_OFF  (320ull * 1024)
#define WSL_OFF   (384ull * 1024)
#define STK_OFF   (448ull * 1024)
#define TILEE_OFF (512ull * 1024)
#define TILEM_OFF (TILEE_OFF + 512)
#define TILEC_OFF (TILEM_OFF + 512)
#define XH_OFF    (1ull * MiB)     // 4 MiB f16
#define HBUF_OFF  (8ull * MiB)     // 64 MiB f16 (hrf f32 8 MiB overlays start)
#define YBUF_OFF  (72ull * MiB)    // 32 MiB f32
#define W1T_OFF   (104ull * MiB)   // 128 MiB f16 [E][F][H]
#define W2T_OFF   (232ull * MiB)   // 128 MiB f16 [E][H][F]
#define WS_NEED_FAST (360ull * MiB)

// ---------------- helpers ----------------
__device__ __forceinline__ void gload16(const void* g, void* l) {
  __builtin_amdgcn_global_load_lds(
      (const __attribute__((address_space(1))) unsigned int*)g,
      (__attribute__((address_space(3))) unsigned int*)l, 16, 0, 0);
}

// fast GELU: tanh-form, hw exp. |err vs exact erf-GELU| ~2e-4 (fine vs 2.5e-2 budget)
__device__ __forceinline__ float gelu_fast(float v) {
  float z = 0.7978845608028654f * (v + 0.044715f * v * v * v);
  float e = __expf(2.f * z);
  float t = 1.f - 2.f / (e + 1.f);
  return 0.5f * v * (1.f + t);
}

// ---------------- small kernels ----------------
__global__ void zero_counts_kernel(int* counts) {
  if (threadIdx.x < E_NUM) counts[threadIdx.x] = 0;
}

// ---------------- device bodies for fused kernels ----------------
__device__ __forceinline__ void cast_x_body(int blk, const float* __restrict__ x,
                                            _Float16* __restrict__ xh) {
  int i = blk * 256 + threadIdx.x;       // 8 elems each
  const floatx4* xin = reinterpret_cast<const floatx4*>(x) + (size_t)i * 2;
  floatx4 a = xin[0], b = xin[1];
  f16x8 o;
  o[0] = (_Float16)a[0]; o[1] = (_Float16)a[1]; o[2] = (_Float16)a[2]; o[3] = (_Float16)a[3];
  o[4] = (_Float16)b[0]; o[5] = (_Float16)b[1]; o[6] = (_Float16)b[2]; o[7] = (_Float16)b[3];
  *reinterpret_cast<f16x8*>(xh + (size_t)i * 8) = o;
}

// transpose-cast one 64x64 tile: W [z][K][N] f32 -> Wt [z][N][K] f16
__device__ __forceinline__ void tcast_body(const float* __restrict__ W,
                                           _Float16* __restrict__ Wt, int K, int N,
                                           int e, int k0, int n0, char* smem) {
  float (*Tt)[68] = (float(*)[68])smem;   // [k][n] pad 68
  const float* We = W + (size_t)e * K * N;
  int t = threadIdx.x;
  int kk = t >> 4, nn = (t & 15) * 4;
#pragma unroll
  for (int j = 0; j < 4; j++) {
    int k = kk + 16 * j;
    floatx4 v = *reinterpret_cast<const floatx4*>(We + (size_t)(k0 + k) * N + n0 + nn);
    *reinterpret_cast<floatx4*>(&Tt[k][nn]) = v;
  }
  __syncthreads();
  int nr = t >> 2, kc = t & 3;
  f16x8 o0, o1;
#pragma unroll
  for (int j = 0; j < 8; j++) {
    o0[j] = (_Float16)Tt[kc * 16 + j][nr];
    o1[j] = (_Float16)Tt[kc * 16 + 8 + j][nr];
  }
  _Float16* dst = Wt + (size_t)e * N * K + (size_t)(n0 + nr) * K + k0 + kc * 16;
  *reinterpret_cast<f16x8*>(dst) = o0;
  *reinterpret_cast<f16x8*>(dst + 8) = o1;
}

// router GEMM1 64x64 tile, near-fp32 via 3-term fp16 split
__device__ __forceinline__ void router_gemm1_body(
    int m0, int n0, const float* __restrict__ x, const float* __restrict__ Wr1,
    const float* __restrict__ br1, float* __restrict__ hrf, char* smem) {
  _Float16 (*Ah)[40] = (_Float16(*)[40])(smem);
  _Float16 (*Al)[40] = (_Float16(*)[40])(smem + 5120);
  _Float16 (*Bh)[40] = (_Float16(*)[40])(smem + 10240);
  _Float16 (*Bl)[40] = (_Float16(*)[40])(smem + 15360);
  int tid = threadIdx.x;
  int arow = tid >> 2, achk = tid & 3;
  const float* Arow = x + (size_t)(m0 + arow) * H_DIM + achk * 8;
  int brow = tid >> 3, bq = tid & 7;

  floatx4 acc[2][2];
#pragma unroll
  for (int i = 0; i < 2; i++)
#pragma unroll
    for (int j = 0; j < 2; j++) acc[i][j] = (floatx4){0.f, 0.f, 0.f, 0.f};

  int wv = tid >> 6, lane = tid & 63;
  int wm = wv >> 1, wn = wv & 1;
  int lrow = lane & 15, lk = (lane >> 4) * 8;

  for (int k0 = 0; k0 < H_DIM; k0 += 32) {
    floatx4 a0 = *reinterpret_cast<const floatx4*>(Arow + k0);
    floatx4 a1 = *reinterpret_cast<const floatx4*>(Arow + k0 + 4);
    f16x8 hv, lv;
#pragma unroll
    for (int j = 0; j < 4; j++) {
      _Float16 hi = (_Float16)a0[j]; hv[j] = hi; lv[j] = (_Float16)(a0[j] - (float)hi);
      _Float16 hi2 = (_Float16)a1[j]; hv[4 + j] = hi2; lv[4 + j] = (_Float16)(a1[j] - (float)hi2);
    }
    *reinterpret_cast<f16x8*>(&Ah[arow][achk * 8]) = hv;
    *reinterpret_cast<f16x8*>(&Al[arow][achk * 8]) = lv;
    const float* wp = Wr1 + (size_t)(k0 + brow) * H_DIM + n0 + bq * 4;
    floatx4 w0 = *reinterpret_cast<const floatx4*>(wp);
    floatx4 w1 = *reinterpret_cast<const floatx4*>(wp + 32);
#pragma unroll
    for (int i = 0; i < 4; i++) {
      _Float16 h0 = (_Float16)w0[i];
      Bh[bq * 4 + i][brow] = h0; Bl[bq * 4 + i][brow] = (_Float16)(w0[i] - (float)h0);
      _Float16 h1 = (_Float16)w1[i];
      Bh[32 + bq * 4 + i][brow] = h1; Bl[32 + bq * 4 + i][brow] = (_Float16)(w1[i] - (float)h1);
    }
    __syncthreads();

    f16x8 ah0 = *reinterpret_cast<const f16x8*>(&Ah[32 * wm + lrow][lk]);
    f16x8 ah1 = *reinterpret_cast<const f16x8*>(&Ah[32 * wm + 16 + lrow][lk]);
    f16x8 al0 = *reinterpret_cast<const f16x8*>(&Al[32 * wm + lrow][lk]);
    f16x8 al1 = *reinterpret_cast<const f16x8*>(&Al[32 * wm + 16 + lrow][lk]);
    f16x8 bh0 = *reinterpret_cast<const f16x8*>(&Bh[32 * wn + lrow][lk]);
    f16x8 bh1 = *reinterpret_cast<const f16x8*>(&Bh[32 * wn + 16 + lrow][lk]);
    f16x8 bl0 = *reinterpret_cast<const f16x8*>(&Bl[32 * wn + lrow][lk]);
    f16x8 bl1 = *reinterpret_cast<const f16x8*>(&Bl[32 * wn + 16 + lrow][lk]);

    acc[0][0] = __builtin_amdgcn_mfma_f32_16x16x32_f16(ah0, bh0, acc[0][0], 0, 0, 0);
    acc[0][0] = __builtin_amdgcn_mfma_f32_16x16x32_f16(ah0, bl0, acc[0][0], 0, 0, 0);
    acc[0][0] = __builtin_amdgcn_mfma_f32_16x16x32_f16(al0, bh0, acc[0][0], 0, 0, 0);
    acc[0][1] = __builtin_amdgcn_mfma_f32_16x16x32_f16(ah0, bh1, acc[0][1], 0, 0, 0);
    acc[0][1] = __builtin_amdgcn_mfma_f32_16x16x32_f16(ah0, bl1, acc[0][1], 0, 0, 0);
    acc[0][1] = __builtin_amdgcn_mfma_f32_16x16x32_f16(al0, bh1, acc[0][1], 0, 0, 0);
    acc[1][0] = __builtin_amdgcn_mfma_f32_16x16x32_f16(ah1, bh0, acc[1][0], 0, 0, 0);
    acc[1][0] = __builtin_amdgcn_mfma_f32_16x16x32_f16(ah1, bl0, acc[1][0], 0, 0, 0);
    acc[1][0] = __builtin_amdgcn_mfma_f32_16x16x32_f16(al1, bh0, acc[1][0], 0, 0, 0);
    acc[1][1] = __builtin_amdgcn_mfma_f32_16x16x32_f16(ah1, bh1, acc[1][1], 0, 0, 0);
    acc[1][1] = __builtin_amdgcn_mfma_f32_16x16x32_f16(ah1, bl1, acc[1][1], 0, 0, 0);
    acc[1][1] = __builtin_amdgcn_mfma_f32_16x16x32_f16(al1, bh1, acc[1][1], 0, 0, 0);
    __syncthreads();
  }

#pragma unroll
  for (int am = 0; am < 2; am++) {
#pragma unroll
    for (int bn = 0; bn < 2; bn++) {
      int col = n0 + 32 * wn + 16 * bn + lrow;
      float bv = br1[col];
#pragma unroll
      for (int r = 0; r < 4; r++) {
        int rowt = 32 * wm + 16 * am + (lane >> 4) * 4 + r;
        float v = acc[am][bn][r] + bv;
        hrf[(size_t)(m0 + rowt) * H_DIM + col] = fmaxf(v, 0.f);
      }
    }
  }
}

// ---------------- fused A: router_gemm1 (512) + tcast W1 (16384) + cast_x (1024) ----------------
#define FA_RG   512
#define FA_TC   16384
#define FA_CX   1024
__global__ __launch_bounds__(256) void fusedA_kernel(
    const float* __restrict__ x, const float* __restrict__ Wr1, const float* __restrict__ br1,
    float* __restrict__ hrf, const float* __restrict__ W1, _Float16* __restrict__ W1t,
    _Float16* __restrict__ xh) {
  __shared__ __align__(16) char smem[20480];
  int bid = blockIdx.x;
  if (bid < FA_RG) {
    router_gemm1_body((bid >> 4) * 64, (bid & 15) * 64, x, Wr1, br1, hrf, smem);
  } else if (bid < FA_RG + FA_TC) {
    int idx = bid - FA_RG;          // W1: K=H_DIM, N=F_DIM
    int nt = idx & 63, kt = (idx >> 6) & 15, e = idx >> 10;
    tcast_body(W1, W1t, H_DIM, F_DIM, e, kt * 64, nt * 64, smem);
  } else {
    cast_x_body(bid - FA_RG - FA_TC, x, xh);
  }
}

// logits = hrf @ Wr2 + br2 ; one wave per token (fp32)
__global__ __launch_bounds__(256) void router_logits_kernel(
    const float* __restrict__ hrf, const float* __restrict__ Wr2,
    const float* __restrict__ br2, float* __restrict__ logits) {
  int t = blockIdx.x * 4 + (threadIdx.x >> 6);
  int lane = threadIdx.x & 63;
  float acc[E_NUM];
#pragma unroll
  for (int e = 0; e < E_NUM; e++) acc[e] = 0.f;
  const float* hr = hrf + (size_t)t * H_DIM;
#pragma unroll 4
  for (int i = 0; i < H_DIM / 64; i++) {
    int k = lane + 64 * i;
    float a = hr[k];
    const floatx4* w4 = reinterpret_cast<const floatx4*>(Wr2 + (size_t)k * E_NUM);
    floatx4 w0 = w4[0], w1 = w4[1], w2 = w4[2], w3 = w4[3];
#pragma unroll
    for (int j = 0; j < 4; j++) {
      acc[j]      += a * w0[j];
      acc[4 + j]  += a * w1[j];
      acc[8 + j]  += a * w2[j];
      acc[12 + j] += a * w3[j];
    }
  }
#pragma unroll
  for (int e = 0; e < E_NUM; e++) {
    float v = acc[e];
    for (int off = 32; off > 0; off >>= 1) v += __shfl_xor(v, off);
    if (lane == e) logits[(size_t)t * E_NUM + e] = v + br2[e];
  }
}

// per-token top-4 + softmax + counts
__global__ void route_kernel(const float* __restrict__ logits, int* __restrict__ topi,
                             float* __restrict__ topw, int* __restrict__ counts) {
  int t = blockIdx.x * 256 + threadIdx.x;
  if (t >= T_TOK) return;
  float lg[E_NUM];
#pragma unroll
  for (int e = 0; e < E_NUM; e++) lg[e] = logits[(size_t)t * E_NUM + e];
  unsigned int used = 0;
  float vals[K_TOP]; int idx[K_TOP];
#pragma unroll
  for (int k = 0; k < K_TOP; k++) {
    float best = -1e30f; int bi = 0;
#pragma unroll
    for (int e = 0; e < E_NUM; e++) {
      if (!((used >> e) & 1u) && lg[e] > best) { best = lg[e]; bi = e; }
    }
    used |= (1u << bi);
    vals[k] = best; idx[k] = bi;
  }
  float m = vals[0];
  float s = 0.f;
  float w[K_TOP];
#pragma unroll
  for (int k = 0; k < K_TOP; k++) { w[k] = expf(vals[k] - m); s += w[k]; }
  float inv = 1.f / s;
#pragma unroll
  for (int k = 0; k < K_TOP; k++) {
    topi[t * K_TOP + k] = idx[k];
    topw[t * K_TOP + k] = w[k] * inv;
    atomicAdd(&counts[idx[k]], 1);
  }
}

// prefix scan + compacted m-tile table (shared by both expert GEMMs)
__global__ void scan_kernel(const int* __restrict__ counts, int* __restrict__ offsets,
                            int* __restrict__ cursor, int* __restrict__ tileE,
                            int* __restrict__ tileM, int* __restrict__ tileC) {
  if (threadIdx.x == 0) {
    int acc = 0;
    offsets[0] = 0;
    for (int e = 0; e < E_NUM; e++) { acc += counts[e]; offsets[e + 1] = acc; }
    int idx = 0;
    for (int e = 0; e < E_NUM; e++) {
      int c = counts[e];
      for (int m0 = 0; m0 < c; m0 += 128) { tileE[idx] = e; tileM[idx] = m0; idx++; }
    }
    tileC[0] = idx;   // <= 79
  }
  if (threadIdx.x < E_NUM) cursor[threadIdx.x] = 0;
}

__global__ void scatter_kernel(const int* __restrict__ topi, const float* __restrict__ topw,
                               const int* __restrict__ offsets, int* __restrict__ cursor,
                               int* __restrict__ tok_of_slot, float* __restrict__ w_of_slot,
                               int* __restrict__ slot_of_tk) {
  int t = blockIdx.x * 256 + threadIdx.x;
  if (t >= T_TOK) return;
#pragma unroll
  for (int k = 0; k < K_TOP; k++) {
    int e = topi[t * K_TOP + k];
    int pos = atomicAdd(&cursor[e], 1);
    int slot = offsets[e] + pos;
    tok_of_slot[slot] = t;
    w_of_slot[slot] = topw[t * K_TOP + k];
    slot_of_tk[t * K_TOP + k] = slot;
  }
}

// out[t][h] = sum_k ybuf[slot_of_tk[t][k]][h]
__global__ void combine_kernel(const float* __restrict__ ybuf, const int* __restrict__ slot_of_tk,
                               float* __restrict__ out) {
  int i = blockIdx.x * 256 + threadIdx.x;
  size_t p = (size_t)i * 4;
  int t = (int)(p >> 10);
  int h = (int)(p & 1023);
  float s0 = 0.f, s1 = 0.f, s2 = 0.f, s3 = 0.f;
#pragma unroll
  for (int k = 0; k < K_TOP; k++) {
    int slot = slot_of_tk[t * K_TOP + k];
    const floatx4 v = *reinterpret_cast<const floatx4*>(ybuf + (size_t)slot * H_DIM + h);
    s0 += v[0]; s1 += v[1]; s2 += v[2]; s3 += v[3];
  }
  floatx4 o = {s0, s1, s2, s3};
  *reinterpret_cast<floatx4*>(out + p) = o;
}

// ---------------- expert GEMM body: 128x128 tile, 2-phase dbuf prefetch ----------------
template <int ACT, bool GATHER, bool SCALE, bool OUTF16>
__device__ __forceinline__ void moe_gemm_body(
    int ti, int n0, const _Float16* __restrict__ A, const _Float16* __restrict__ Bt,
    const float* __restrict__ bias, void* __restrict__ Out,
    const int* __restrict__ offsets, const int* __restrict__ toklist,
    const float* __restrict__ wslot, const int* __restrict__ tileE,
    const int* __restrict__ tileM, const int* __restrict__ tileC,
    int N, int K, char* smem) {
  if (ti >= tileC[0]) return;
  int e = tileE[ti], m0 = tileM[ti];
  int base = offsets[e], cnt = offsets[e + 1] - base;

  _Float16 (*As)[128][32] = (_Float16(*)[128][32])(smem);
  _Float16 (*Bs)[128][32] = (_Float16(*)[128][32])(smem + 16384);

  int tid = threadIdx.x;
  int w = tid >> 6, lane = tid & 63;
  int wm = w >> 1, wn = w & 1;
  int lrow = lane & 15, lkc = (lane >> 4) * 8;

  int ar0 = w * 32 + (lane >> 2);
  int ar1 = ar0 + 16;
  int ach = (lane & 3) * 8;
  int mr0 = m0 + ar0; if (mr0 >= cnt) mr0 = cnt - 1;
  int mr1 = m0 + ar1; if (mr1 >= cnt) mr1 = cnt - 1;
  const _Float16* gA0 = A + (long)(GATHER ? toklist[base + mr0] : (base + mr0)) * K + ach;
  const _Float16* gA1 = A + (long)(GATHER ? toklist[base + mr1] : (base + mr1)) * K + ach;
  const _Float16* bge = Bt + (size_t)e * N * K;
  const _Float16* gB0 = bge + (long)(n0 + ar0) * K + ach;
  const _Float16* gB1 = bge + (long)(n0 + ar1) * K + ach;

#define STAGE2(buf, kk) do { \
    gload16(gA0 + (kk), &As[buf][w * 32][0]); \
    gload16(gA1 + (kk), &As[buf][w * 32 + 16][0]); \
    gload16(gB0 + (kk), &Bs[buf][w * 32][0]); \
    gload16(gB1 + (kk), &Bs[buf][w * 32 + 16][0]); \
  } while (0)

  floatx4 acc[4][4];
#pragma unroll
  for (int i = 0; i < 4; i++)
#pragma unroll
    for (int j = 0; j < 4; j++) acc[i][j] = (floatx4){0.f, 0.f, 0.f, 0.f};

  STAGE2(0, 0);
  __syncthreads();

  int nk = K >> 5;
  for (int it = 0; it < nk; ++it) {
    int cur = it & 1;
    if (it + 1 < nk) STAGE2(cur ^ 1, (it + 1) << 5);

    f16x8 a[4], b[4];
#pragma unroll
    for (int i = 0; i < 4; i++) {
      a[i] = *reinterpret_cast<const f16x8*>(&As[cur][wm * 64 + i * 16 + lrow][lkc]);
      b[i] = *reinterpret_cast<const f16x8*>(&Bs[cur][wn * 64 + i * 16 + lrow][lkc]);
    }
#pragma unroll
    for (int i = 0; i < 4; i++)
#pragma unroll
      for (int j = 0; j < 4; j++)
        acc[i][j] = __builtin_amdgcn_mfma_f32_16x16x32_f16(a[i], b[j], acc[i][j], 0, 0, 0);

    __syncthreads();
  }
#undef STAGE2

  const float* be = bias + (size_t)e * N;
#pragma unroll
  for (int fm = 0; fm < 4; fm++) {
#pragma unroll
    for (int fn = 0; fn < 4; fn++) {
      int col = n0 + wn * 64 + fn * 16 + lrow;
      float bv = be[col];
#pragma unroll
      for (int r = 0; r < 4; r++) {
        int rowt = wm * 64 + fm * 16 + (lane >> 4) * 4 + r;
        int mg = m0 + rowt;
        if (mg < cnt) {
          float v = acc[fm][fn][r] + bv;
          if (ACT == 2) v = gelu_fast(v);
          long orow = base + mg;
          if (SCALE) v *= wslot[orow];
          if (OUTF16)
            ((_Float16*)Out)[orow * (long)N + col] = (_Float16)v;
          else
            ((float*)Out)[orow * (long)N + col] = v;
        }
      }
    }
  }
}

// ---------------- fused B: expert GEMM1 (2560) + tcast W2 (16384) ----------------
#define FB_G1 (32 * 80)
#define FB_TC 16384
__global__ __launch_bounds__(256) void fusedB_kernel(
    const _Float16* __restrict__ xh, const _Float16* __restrict__ W1t,
    const float* __restrict__ b1, _Float16* __restrict__ hbuf,
    const int* __restrict__ offsets, const int* __restrict__ toklist,
    const int* __restrict__ tileE, const int* __restrict__ tileM, const int* __restrict__ tileC,
    const float* __restrict__ W2, _Float16* __restrict__ W2t) {
  __shared__ __align__(16) char smem[32768];
  int bid = blockIdx.x;
  if (bid < FB_G1) {
    moe_gemm_body<2, true, false, true>(bid >> 5, (bid & 31) * 128, xh, W1t, b1, (void*)hbuf,
                                        offsets, toklist, nullptr, tileE, tileM, tileC,
                                        F_DIM, H_DIM, smem);
  } else {
    int idx = bid - FB_G1;          // W2: K=F_DIM, N=H_DIM
    int nt = idx & 15, kt = (idx >> 4) & 63, e = idx >> 10;
    tcast_body(W2, W2t, F_DIM, H_DIM, e, kt * 64, nt * 64, smem);
  }
}

// expert GEMM2 standalone
__global__ __launch_bounds__(256) void moe_gemm2_kernel(
    const _Float16* __restrict__ hbuf, const _Float16* __restrict__ W2t,
    const float* __restrict__ b2, float* __restrict__ ybuf,
    const int* __restrict__ offsets, const float* __restrict__ wslot,
    const int* __restrict__ tileE, const int* __restrict__ tileM, const int* __restrict__ tileC) {
  __shared__ __align__(16) char smem[32768];
  moe_gemm_body<0, false, true, false>(blockIdx.y, blockIdx.x * 128, hbuf, W2t, b2, (void*)ybuf,
                                       offsets, nullptr, wslot, tileE, tileM, tileC,
                                       H_DIM, F_DIM, smem);
}

// ---------------- FALLBACK MFMA GEMM (in-flight convert, small ws) ----------------
template <int ACT, bool GATHER, bool OFFS, bool SCALE, bool OUTF16>
__global__ __launch_bounds__(256) void moe_gemm(
    const _Float16* __restrict__ A, const float* __restrict__ W,
    const float* __restrict__ bias, void* __restrict__ Out,
    const int* __restrict__ offsets, const int* __restrict__ toklist,
    const float* __restrict__ wslot, int M, int N, int K) {
  int e = blockIdx.z;
  int base = 0, cnt = M;
  if (OFFS) { base = offsets[e]; cnt = offsets[e + 1] - base; }
  int m0 = blockIdx.y * 64;
  if (m0 >= cnt) return;
  int n0 = blockIdx.x * 64;
  const float* We = W + (size_t)e * K * N;
  const float* be = bias + (size_t)e * N;

  __shared__ _Float16 As[64][40];
  __shared__ _Float16 Bs[64][40];

  int tid = threadIdx.x;
  int arow = tid >> 2, achk = tid & 3;
  int am_idx = m0 + arow; if (am_idx > cnt - 1) am_idx = cnt - 1;
  long arowg = GATHER ? (long)toklist[base + am_idx] : (long)(base + am_idx);
  const _Float16* Arow = A + arowg * (long)K + achk * 8;

  int brow = tid >> 3, bq = tid & 7;

  floatx4 acc[2][2];
#pragma unroll
  for (int i = 0; i < 2; i++)
#pragma unroll
    for (int j = 0; j < 2; j++) acc[i][j] = (floatx4){0.f, 0.f, 0.f, 0.f};

  int wv = tid >> 6, lane = tid & 63;
  int wm = wv >> 1, wn = wv & 1;
  int lrow = lane & 15, lk = (lane >> 4) * 8;

  for (int k0 = 0; k0 < K; k0 += 32) {
    *reinterpret_cast<f16x8*>(&As[arow][achk * 8]) = *reinterpret_cast<const f16x8*>(Arow + k0);
    const float* wp = We + (size_t)(k0 + brow) * N + n0 + bq * 4;
    floatx4 w0 = *reinterpret_cast<const floatx4*>(wp);
    floatx4 w1 = *reinterpret_cast<const floatx4*>(wp + 32);
#pragma unroll
    for (int i = 0; i < 4; i++) {
      Bs[bq * 4 + i][brow]      = (_Float16)w0[i];
      Bs[32 + bq * 4 + i][brow] = (_Float16)w1[i];
    }
    __syncthreads();

    f16x8 a0 = *reinterpret_cast<const f16x8*>(&As[32 * wm + lrow][lk]);
    f16x8 a1 = *reinterpret_cast<const f16x8*>(&As[32 * wm + 16 + lrow][lk]);
    f16x8 b0 = *reinterpret_cast<const f16x8*>(&Bs[32 * wn + lrow][lk]);
    f16x8 b1 = *reinterpret_cast<const f16x8*>(&Bs[32 * wn + 16 + lrow][lk]);
    acc[0][0] = __builtin_amdgcn_mfma_f32_16x16x32_f16(a0, b0, acc[0][0], 0, 0, 0);
    acc[0][1] = __builtin_amdgcn_mfma_f32_16x16x32_f16(a0, b1, acc[0][1], 0, 0, 0);
    acc[1][0] = __builtin_amdgcn_mfma_f32_16x16x32_f16(a1, b0, acc[1][0], 0, 0, 0);
    acc[1][1] = __builtin_amdgcn_mfma_f32_16x16x32_f16(a1, b1, acc[1][1], 0, 0, 0);
    __syncthreads();
  }

#pragma unroll
  for (int am = 0; am < 2; am++) {
#pragma unroll
    for (int bn = 0; bn < 2; bn++) {
      int col = n0 + 32 * wn + 16 * bn + lrow;
      float bv = be[col];
#pragma unroll
      for (int r = 0; r < 4; r++) {
        int rowt = 32 * wm + 16 * am + (lane >> 4) * 4 + r;
        int mg = m0 + rowt;
        if (mg < cnt) {
          float v = acc[am][bn][r] + bv;
          if (ACT == 2) v = gelu_fast(v);
          long orow = base + mg;
          if (SCALE) v *= wslot[orow];
          if (OUTF16)
            ((_Float16*)Out)[orow * (long)N + col] = (_Float16)v;
          else
            ((float*)Out)[orow * (long)N + col] = v;
        }
      }
    }
  }
}

__global__ void cast_x_kernel(const float* __restrict__ x, _Float16* __restrict__ xh) {
  cast_x_body(blockIdx.x, x, xh);
}

__global__ __launch_bounds__(256) void router_gemm1_kernel(
    const float* __restrict__ x, const float* __restrict__ Wr1,
    const float* __restrict__ br1, float* __restrict__ hrf) {
  __shared__ __align__(16) char smem[20480];
  router_gemm1_body(blockIdx.y * 64, blockIdx.x * 64, x, Wr1, br1, hrf, smem);
}

// ---------------- launch ----------------
extern "C" void kernel_launch(void* const* d_in, const int* in_sizes, int n_in,
                              void* d_out, int out_size, void* d_ws, size_t ws_size,
                              hipStream_t stream) {
  const float* x   = (const float*)d_in[0];
  const float* Wr1 = (const float*)d_in[1];
  const float* br1 = (const float*)d_in[2];
  const float* Wr2 = (const float*)d_in[3];
  const float* br2 = (const float*)d_in[4];
  const float* W1  = (const float*)d_in[5];
  const float* b1  = (const float*)d_in[6];
  const float* W2  = (const float*)d_in[7];
  const float* b2  = (const float*)d_in[8];
  float* out = (float*)d_out;

  char* ws = (char*)d_ws;
  float* logits = (float*)(ws + LOGIT_OFF);
  int*   topi   = (int*)(ws + TOPI_OFF);
  float* topw   = (float*)(ws + TOPW_OFF);
  int*   counts = (int*)(ws + CNT_OFF);
  int*   offs   = (int*)(ws + OFFS_OFF);
  int*   cursor = (int*)(ws + CUR_OFF);
  int*   toks   = (int*)(ws + TOKS_OFF);
  float* wsl    = (float*)(ws + WSL_OFF);
  int*   stk    = (int*)(ws + STK_OFF);
  int*   tileE  = (int*)(ws + TILEE_OFF);
  int*   tileM  = (int*)(ws + TILEM_OFF);
  int*   tileC  = (int*)(ws + TILEC_OFF);
  _Float16* xh   = (_Float16*)(ws + XH_OFF);
  float*    hrf  = (float*)(ws + HBUF_OFF);
  _Float16* hbuf = (_Float16*)(ws + HBUF_OFF);
  float*    ybuf = (float*)(ws + YBUF_OFF);
  _Float16* W1t  = (_Float16*)(ws + W1T_OFF);
  _Float16* W2t  = (_Float16*)(ws + W2T_OFF);

  bool fast = ws_size >= WS_NEED_FAST;

  zero_counts_kernel<<<1, 64, 0, stream>>>(counts);

  if (fast) {
    // router GEMM1 + tcast(W1) + cast_x fused by grid range
    fusedA_kernel<<<FA_RG + FA_TC + FA_CX, 256, 0, stream>>>(x, Wr1, br1, hrf, W1, W1t, xh);
  } else {
    cast_x_kernel<<<(T_TOK * H_DIM / 8) / 256, 256, 0, stream>>>(x, xh);
    router_gemm1_kernel<<<dim3(H_DIM / 64, T_TOK / 64), 256, 0, stream>>>(x, Wr1, br1, hrf);
  }

  router_logits_kernel<<<T_TOK / 4, 256, 0, stream>>>(hrf, Wr2, br2, logits);
  route_kernel<<<T_TOK / 256, 256, 0, stream>>>(logits, topi, topw, counts);
  scan_kernel<<<1, 64, 0, stream>>>(counts, offs, cursor, tileE, tileM, tileC);
  scatter_kernel<<<T_TOK / 256, 256, 0, stream>>>(topi, topw, offs, cursor, toks, wsl, stk);

  if (fast) {
    // expert GEMM1 + tcast(W2) fused
    fusedB_kernel<<<FB_G1 + FB_TC, 256, 0, stream>>>(xh, W1t, b1, hbuf, offs, toks,
                                                     tileE, tileM, tileC, W2, W2t);
    moe_gemm2_kernel<<<dim3(H_DIM / 128, 80), 256, 0, stream>>>(hbuf, W2t, b2, ybuf, offs, wsl,
                                                                tileE, tileM, tileC);
  } else {
    moe_gemm<2, true, true, false, true><<<dim3(F_DIM / 64, T_TOK / 64, E_NUM), 256, 0, stream>>>(
        xh, W1, b1, (void*)hbuf, offs, toks, nullptr, T_TOK, F_DIM, H_DIM);
    moe_gemm<0, false, true, true, false><<<dim3(H_DIM / 64, T_TOK / 64, E_NUM), 256, 0, stream>>>(
        hbuf, W2, b2, (void*)ybuf, offs, nullptr, wsl, T_TOK, H_DIM, F_DIM);
  }

  combine_kernel<<<(T_TOK * H_DIM / 4) / 256, 256, 0, stream>>>(ybuf, stk, out);
}

// Round 6
// 454.114 us; speedup vs baseline: 1.5043x; 1.0925x over previous
//
#include <hip/hip_runtime.h>
#include <hip/hip_bf16.h>

// ---------------- problem constants ----------------
#define T_TOK 2048
#define H_DIM 1024
#define F_DIM 4096
#define E_NUM 16
#define K_TOP 4

typedef float    floatx4 __attribute__((ext_vector_type(4)));
typedef _Float16 f16x8   __attribute__((ext_vector_type(8)));
typedef _Float16 f16x4   __attribute__((ext_vector_type(4)));

// ---------------- ws layout (bytes) ----------------
#define MiB (1024ull * 1024ull)
#define LOGIT_OFF ((size_t)0)
#define OFFS_OFF  (256ull * 1024)
#define TOKS_OFF  (320ull * 1024)
#define WSL_OFF   (384ull * 1024)
#define STK_OFF   (448ull * 1024)
#define TILEE_OFF (512ull * 1024)
#define TILEM_OFF (TILEE_OFF + 512)
#define TILEC_OFF (TILEM_OFF + 512)
#define XH_OFF    (1ull * MiB)     // 4 MiB f16
#define HBUF_OFF  (8ull * MiB)     // 64 MiB f16 (hrf f32 8 MiB overlays start)
#define YBUF_OFF  (72ull * MiB)    // 16 MiB f16
#define W1T_OFF   (104ull * MiB)   // 128 MiB f16 [E][F][H]
#define W2T_OFF   (232ull * MiB)   // 128 MiB f16 [E][H][F]
#define WS_NEED_FAST (360ull * MiB)

// ---------------- helpers ----------------
__device__ __forceinline__ void gload16(const void* g, void* l) {
  __builtin_amdgcn_global_load_lds(
      (const __attribute__((address_space(1))) unsigned int*)g,
      (__attribute__((address_space(3))) unsigned int*)l, 16, 0, 0);
}

// fast GELU: tanh-form, hw exp
__device__ __forceinline__ float gelu_fast(float v) {
  float z = 0.7978845608028654f * (v + 0.044715f * v * v * v);
  float e = __expf(2.f * z);
  float t = 1.f - 2.f / (e + 1.f);
  return 0.5f * v * (1.f + t);
}

// ---------------- device bodies ----------------
__device__ __forceinline__ void cast_x_body(int blk, const float* __restrict__ x,
                                            _Float16* __restrict__ xh) {
  int i = blk * 256 + threadIdx.x;
  const floatx4* xin = reinterpret_cast<const floatx4*>(x) + (size_t)i * 2;
  floatx4 a = xin[0], b = xin[1];
  f16x8 o;
  o[0] = (_Float16)a[0]; o[1] = (_Float16)a[1]; o[2] = (_Float16)a[2]; o[3] = (_Float16)a[3];
  o[4] = (_Float16)b[0]; o[5] = (_Float16)b[1]; o[6] = (_Float16)b[2]; o[7] = (_Float16)b[3];
  *reinterpret_cast<f16x8*>(xh + (size_t)i * 8) = o;
}

// transpose-cast one 64x64 tile: W [z][K][N] f32 -> Wt [z][N][K] f16
__device__ __forceinline__ void tcast_body(const float* __restrict__ W,
                                           _Float16* __restrict__ Wt, int K, int N,
                                           int e, int k0, int n0, char* smem) {
  float (*Tt)[68] = (float(*)[68])smem;
  const float* We = W + (size_t)e * K * N;
  int t = threadIdx.x;
  int kk = t >> 4, nn = (t & 15) * 4;
#pragma unroll
  for (int j = 0; j < 4; j++) {
    int k = kk + 16 * j;
    floatx4 v = *reinterpret_cast<const floatx4*>(We + (size_t)(k0 + k) * N + n0 + nn);
    *reinterpret_cast<floatx4*>(&Tt[k][nn]) = v;
  }
  __syncthreads();
  int nr = t >> 2, kc = t & 3;
  f16x8 o0, o1;
#pragma unroll
  for (int j = 0; j < 8; j++) {
    o0[j] = (_Float16)Tt[kc * 16 + j][nr];
    o1[j] = (_Float16)Tt[kc * 16 + 8 + j][nr];
  }
  _Float16* dst = Wt + (size_t)e * N * K + (size_t)(n0 + nr) * K + k0 + kc * 16;
  *reinterpret_cast<f16x8*>(dst) = o0;
  *reinterpret_cast<f16x8*>(dst + 8) = o1;
}

// router GEMM1 64x64 tile, near-fp32 via 3-term fp16 split
__device__ __forceinline__ void router_gemm1_body(
    int m0, int n0, const float* __restrict__ x, const float* __restrict__ Wr1,
    const float* __restrict__ br1, float* __restrict__ hrf, char* smem) {
  _Float16 (*Ah)[40] = (_Float16(*)[40])(smem);
  _Float16 (*Al)[40] = (_Float16(*)[40])(smem + 5120);
  _Float16 (*Bh)[40] = (_Float16(*)[40])(smem + 10240);
  _Float16 (*Bl)[40] = (_Float16(*)[40])(smem + 15360);
  int tid = threadIdx.x;
  int arow = tid >> 2, achk = tid & 3;
  const float* Arow = x + (size_t)(m0 + arow) * H_DIM + achk * 8;
  int brow = tid >> 3, bq = tid & 7;

  floatx4 acc[2][2];
#pragma unroll
  for (int i = 0; i < 2; i++)
#pragma unroll
    for (int j = 0; j < 2; j++) acc[i][j] = (floatx4){0.f, 0.f, 0.f, 0.f};

  int wv = tid >> 6, lane = tid & 63;
  int wm = wv >> 1, wn = wv & 1;
  int lrow = lane & 15, lk = (lane >> 4) * 8;

  for (int k0 = 0; k0 < H_DIM; k0 += 32) {
    floatx4 a0 = *reinterpret_cast<const floatx4*>(Arow + k0);
    floatx4 a1 = *reinterpret_cast<const floatx4*>(Arow + k0 + 4);
    f16x8 hv, lv;
#pragma unroll
    for (int j = 0; j < 4; j++) {
      _Float16 hi = (_Float16)a0[j]; hv[j] = hi; lv[j] = (_Float16)(a0[j] - (float)hi);
      _Float16 hi2 = (_Float16)a1[j]; hv[4 + j] = hi2; lv[4 + j] = (_Float16)(a1[j] - (float)hi2);
    }
    *reinterpret_cast<f16x8*>(&Ah[arow][achk * 8]) = hv;
    *reinterpret_cast<f16x8*>(&Al[arow][achk * 8]) = lv;
    const float* wp = Wr1 + (size_t)(k0 + brow) * H_DIM + n0 + bq * 4;
    floatx4 w0 = *reinterpret_cast<const floatx4*>(wp);
    floatx4 w1 = *reinterpret_cast<const floatx4*>(wp + 32);
#pragma unroll
    for (int i = 0; i < 4; i++) {
      _Float16 h0 = (_Float16)w0[i];
      Bh[bq * 4 + i][brow] = h0; Bl[bq * 4 + i][brow] = (_Float16)(w0[i] - (float)h0);
      _Float16 h1 = (_Float16)w1[i];
      Bh[32 + bq * 4 + i][brow] = h1; Bl[32 + bq * 4 + i][brow] = (_Float16)(w1[i] - (float)h1);
    }
    __syncthreads();

    f16x8 ah0 = *reinterpret_cast<const f16x8*>(&Ah[32 * wm + lrow][lk]);
    f16x8 ah1 = *reinterpret_cast<const f16x8*>(&Ah[32 * wm + 16 + lrow][lk]);
    f16x8 al0 = *reinterpret_cast<const f16x8*>(&Al[32 * wm + lrow][lk]);
    f16x8 al1 = *reinterpret_cast<const f16x8*>(&Al[32 * wm + 16 + lrow][lk]);
    f16x8 bh0 = *reinterpret_cast<const f16x8*>(&Bh[32 * wn + lrow][lk]);
    f16x8 bh1 = *reinterpret_cast<const f16x8*>(&Bh[32 * wn + 16 + lrow][lk]);
    f16x8 bl0 = *reinterpret_cast<const f16x8*>(&Bl[32 * wn + lrow][lk]);
    f16x8 bl1 = *reinterpret_cast<const f16x8*>(&Bl[32 * wn + 16 + lrow][lk]);

    acc[0][0] = __builtin_amdgcn_mfma_f32_16x16x32_f16(ah0, bh0, acc[0][0], 0, 0, 0);
    acc[0][0] = __builtin_amdgcn_mfma_f32_16x16x32_f16(ah0, bl0, acc[0][0], 0, 0, 0);
    acc[0][0] = __builtin_amdgcn_mfma_f32_16x16x32_f16(al0, bh0, acc[0][0], 0, 0, 0);
    acc[0][1] = __builtin_amdgcn_mfma_f32_16x16x32_f16(ah0, bh1, acc[0][1], 0, 0, 0);
    acc[0][1] = __builtin_amdgcn_mfma_f32_16x16x32_f16(ah0, bl1, acc[0][1], 0, 0, 0);
    acc[0][1] = __builtin_amdgcn_mfma_f32_16x16x32_f16(al0, bh1, acc[0][1], 0, 0, 0);
    acc[1][0] = __builtin_amdgcn_mfma_f32_16x16x32_f16(ah1, bh0, acc[1][0], 0, 0, 0);
    acc[1][0] = __builtin_amdgcn_mfma_f32_16x16x32_f16(ah1, bl0, acc[1][0], 0, 0, 0);
    acc[1][0] = __builtin_amdgcn_mfma_f32_16x16x32_f16(al1, bh0, acc[1][0], 0, 0, 0);
    acc[1][1] = __builtin_amdgcn_mfma_f32_16x16x32_f16(ah1, bh1, acc[1][1], 0, 0, 0);
    acc[1][1] = __builtin_amdgcn_mfma_f32_16x16x32_f16(ah1, bl1, acc[1][1], 0, 0, 0);
    acc[1][1] = __builtin_amdgcn_mfma_f32_16x16x32_f16(al1, bh1, acc[1][1], 0, 0, 0);
    __syncthreads();
  }

#pragma unroll
  for (int am = 0; am < 2; am++) {
#pragma unroll
    for (int bn = 0; bn < 2; bn++) {
      int col = n0 + 32 * wn + 16 * bn + lrow;
      float bv = br1[col];
#pragma unroll
      for (int r = 0; r < 4; r++) {
        int rowt = 32 * wm + 16 * am + (lane >> 4) * 4 + r;
        float v = acc[am][bn][r] + bv;
        hrf[(size_t)(m0 + rowt) * H_DIM + col] = fmaxf(v, 0.f);
      }
    }
  }
}

// ---------------- fused A: router_gemm1 (512) + tcast W1 (16384) + cast_x (1024) ------------
#define FA_RG   512
#define FA_TC   16384
#define FA_CX   1024
__global__ __launch_bounds__(256) void fusedA_kernel(
    const float* __restrict__ x, const float* __restrict__ Wr1, const float* __restrict__ br1,
    float* __restrict__ hrf, const float* __restrict__ W1, _Float16* __restrict__ W1t,
    _Float16* __restrict__ xh) {
  __shared__ __align__(16) char smem[20480];
  int bid = blockIdx.x;
  if (bid < FA_RG) {
    router_gemm1_body((bid >> 4) * 64, (bid & 15) * 64, x, Wr1, br1, hrf, smem);
  } else if (bid < FA_RG + FA_TC) {
    int idx = bid - FA_RG;
    int nt = idx & 63, kt = (idx >> 6) & 15, e = idx >> 10;
    tcast_body(W1, W1t, H_DIM, F_DIM, e, kt * 64, nt * 64, smem);
  } else {
    cast_x_body(bid - FA_RG - FA_TC, x, xh);
  }
}

// logits = hrf @ Wr2 + br2 ; one wave per token (fp32)
__global__ __launch_bounds__(256) void router_logits_kernel(
    const float* __restrict__ hrf, const float* __restrict__ Wr2,
    const float* __restrict__ br2, float* __restrict__ logits) {
  int t = blockIdx.x * 4 + (threadIdx.x >> 6);
  int lane = threadIdx.x & 63;
  float acc[E_NUM];
#pragma unroll
  for (int e = 0; e < E_NUM; e++) acc[e] = 0.f;
  const float* hr = hrf + (size_t)t * H_DIM;
#pragma unroll 4
  for (int i = 0; i < H_DIM / 64; i++) {
    int k = lane + 64 * i;
    float a = hr[k];
    const floatx4* w4 = reinterpret_cast<const floatx4*>(Wr2 + (size_t)k * E_NUM);
    floatx4 w0 = w4[0], w1 = w4[1], w2 = w4[2], w3 = w4[3];
#pragma unroll
    for (int j = 0; j < 4; j++) {
      acc[j]      += a * w0[j];
      acc[4 + j]  += a * w1[j];
      acc[8 + j]  += a * w2[j];
      acc[12 + j] += a * w3[j];
    }
  }
#pragma unroll
  for (int e = 0; e < E_NUM; e++) {
    float v = acc[e];
    for (int off = 32; off > 0; off >>= 1) v += __shfl_xor(v, off);
    if (lane == e) logits[(size_t)t * E_NUM + e] = v + br2[e];
  }
}

// merged top-k + softmax + scan + tile table + scatter; one block of 1024 threads
__global__ __launch_bounds__(1024) void routing_kernel(
    const float* __restrict__ logits, int* __restrict__ offs,
    int* __restrict__ toks, float* __restrict__ wsl, int* __restrict__ stk,
    int* __restrict__ tileE, int* __restrict__ tileM, int* __restrict__ tileC) {
  __shared__ int cnt[E_NUM], cur[E_NUM], loff[E_NUM + 1];
  int tid = threadIdx.x;
  if (tid < E_NUM) { cnt[tid] = 0; cur[tid] = 0; }
  __syncthreads();
  int ti[2][K_TOP]; float tw[2][K_TOP];
#pragma unroll
  for (int u = 0; u < 2; u++) {
    int t = u * 1024 + tid;
    float lg[E_NUM];
#pragma unroll
    for (int e = 0; e < E_NUM; e++) lg[e] = logits[(size_t)t * E_NUM + e];
    unsigned int used = 0;
    float vals[K_TOP];
#pragma unroll
    for (int k = 0; k < K_TOP; k++) {
      float best = -1e30f; int bi = 0;
#pragma unroll
      for (int e = 0; e < E_NUM; e++) {
        if (!((used >> e) & 1u) && lg[e] > best) { best = lg[e]; bi = e; }
      }
      used |= (1u << bi);
      vals[k] = best; ti[u][k] = bi;
    }
    float m = vals[0], s = 0.f;
#pragma unroll
    for (int k = 0; k < K_TOP; k++) { tw[u][k] = expf(vals[k] - m); s += tw[u][k]; }
    float inv = 1.f / s;
#pragma unroll
    for (int k = 0; k < K_TOP; k++) {
      tw[u][k] *= inv;
      atomicAdd(&cnt[ti[u][k]], 1);
    }
  }
  __syncthreads();
  if (tid == 0) {
    int acc = 0;
    loff[0] = 0; offs[0] = 0;
    for (int e = 0; e < E_NUM; e++) { acc += cnt[e]; loff[e + 1] = acc; offs[e + 1] = acc; }
    int idx = 0;
    for (int e = 0; e < E_NUM; e++) {
      for (int m0 = 0; m0 < cnt[e]; m0 += 128) { tileE[idx] = e; tileM[idx] = m0; idx++; }
    }
    tileC[0] = idx;
  }
  __syncthreads();
#pragma unroll
  for (int u = 0; u < 2; u++) {
    int t = u * 1024 + tid;
#pragma unroll
    for (int k = 0; k < K_TOP; k++) {
      int e = ti[u][k];
      int pos = atomicAdd(&cur[e], 1);
      int slot = loff[e] + pos;
      toks[slot] = t;
      wsl[slot] = tw[u][k];
      stk[t * K_TOP + k] = slot;
    }
  }
}

// out[t][h] = sum_k ybuf[stk[t][k]][h] ; ybuf f16
__global__ void combine_kernel(const _Float16* __restrict__ ybuf, const int* __restrict__ stk,
                               float* __restrict__ out) {
  int i = blockIdx.x * 256 + threadIdx.x;
  size_t p = (size_t)i * 8;
  int t = (int)(p >> 10);
  int h = (int)(p & 1023);
  float s[8] = {0.f, 0.f, 0.f, 0.f, 0.f, 0.f, 0.f, 0.f};
#pragma unroll
  for (int k = 0; k < K_TOP; k++) {
    int slot = stk[t * K_TOP + k];
    f16x8 v = *reinterpret_cast<const f16x8*>(ybuf + (size_t)slot * H_DIM + h);
#pragma unroll
    for (int j = 0; j < 8; j++) s[j] += (float)v[j];
  }
  floatx4 o0 = {s[0], s[1], s[2], s[3]};
  floatx4 o1 = {s[4], s[5], s[6], s[7]};
  *reinterpret_cast<floatx4*>(out + p) = o0;
  *reinterpret_cast<floatx4*>(out + p + 4) = o1;
}

// ---------------- expert GEMM body: 128x128, 3-buffer counted-vmcnt, swizzled LDS ----------
// swizzle: logical k-chunk c of row r stored at phys chunk c ^ ((r>>1)&3)  (2-way banks, free)
// write side via pre-swizzled global source (gload_lds dest stays linear: lane L -> row L>>2, chunk L&3)
template <int KK, int ACT, bool GATHER, bool SCALE>
__device__ __forceinline__ void moe_gemm_body(
    int ti, int n0, const _Float16* __restrict__ A, const _Float16* __restrict__ Bt,
    const float* __restrict__ bias, _Float16* __restrict__ Out,
    const int* __restrict__ offsets, const int* __restrict__ toklist,
    const float* __restrict__ wslot, const int* __restrict__ tileE,
    const int* __restrict__ tileM, const int* __restrict__ tileC,
    int N, char* smem) {
  if (ti >= tileC[0]) return;
  const int K = KK;
  int e = tileE[ti], m0 = tileM[ti];
  int base = offsets[e], cnt = offsets[e + 1] - base;

  _Float16 (*As)[128][32] = reinterpret_cast<_Float16(*)[128][32]>(smem);
  _Float16 (*Bs)[128][32] = reinterpret_cast<_Float16(*)[128][32]>(smem + 24576);

  int tid = threadIdx.x;
  int w = tid >> 6, lane = tid & 63;
  int wm = w >> 1, wn = w & 1;
  int lrow = lane & 15;

  // staging source (pre-swizzled chunk)
  int ar0 = w * 32 + (lane >> 2);
  int ar1 = ar0 + 16;
  int ach = (((lane & 3) ^ ((lane >> 3) & 3))) * 8;   // xor = ((row>>1)&3), row = L>>2 (+w*32, +16 drop out)
  int mr0 = m0 + ar0; if (mr0 >= cnt) mr0 = cnt - 1;
  int mr1 = m0 + ar1; if (mr1 >= cnt) mr1 = cnt - 1;
  const _Float16* gA0 = A + (long)(GATHER ? toklist[base + mr0] : (base + mr0)) * K + ach;
  const _Float16* gA1 = A + (long)(GATHER ? toklist[base + mr1] : (base + mr1)) * K + ach;
  const _Float16* bge = Bt + (size_t)e * N * K;
  const _Float16* gB0 = bge + (long)(n0 + ar0) * K + ach;
  const _Float16* gB1 = bge + (long)(n0 + ar1) * K + ach;

  // read-side swizzled chunk (per-lane constant): phys = (lane>>4) ^ ((lrow>>1)&3)
  int phys8 = ((lane >> 4) ^ ((lrow >> 1) & 3)) * 8;

#define STAGE3(buf, kk) do { \
    gload16(gA0 + (kk), &As[buf][w * 32][0]); \
    gload16(gA1 + (kk), &As[buf][w * 32 + 16][0]); \
    gload16(gB0 + (kk), &Bs[buf][w * 32][0]); \
    gload16(gB1 + (kk), &Bs[buf][w * 32 + 16][0]); \
  } while (0)

#define COMPUTE3(buf) do { \
    f16x8 a[4], b[4]; \
    _Pragma("unroll") \
    for (int i = 0; i < 4; i++) { \
      a[i] = *reinterpret_cast<const f16x8*>(&As[buf][wm * 64 + i * 16 + lrow][phys8]); \
      b[i] = *reinterpret_cast<const f16x8*>(&Bs[buf][wn * 64 + i * 16 + lrow][phys8]); \
    } \
    __builtin_amdgcn_s_setprio(1); \
    _Pragma("unroll") \
    for (int i = 0; i < 4; i++) \
      _Pragma("unroll") \
      for (int j = 0; j < 4; j++) \
        acc[i][j] = __builtin_amdgcn_mfma_f32_16x16x32_f16(a[i], b[j], acc[i][j], 0, 0, 0); \
    __builtin_amdgcn_s_setprio(0); \
  } while (0)

  floatx4 acc[4][4];
#pragma unroll
  for (int i = 0; i < 4; i++)
#pragma unroll
    for (int j = 0; j < 4; j++) acc[i][j] = (floatx4){0.f, 0.f, 0.f, 0.f};

  constexpr int nk = KK / 32;
  STAGE3(0, 0);
  STAGE3(1, 32);

#pragma unroll 3
  for (int it = 0; it < nk - 1; ++it) {
    // buffer `it` was staged 2 tiles ago; 4 newer loads (buffer it+1) may stay in flight
    asm volatile("s_waitcnt vmcnt(4)" ::: "memory");
    __builtin_amdgcn_s_barrier();
    if (it + 2 < nk) STAGE3((it + 2) % 3, (it + 2) * 32);
    COMPUTE3(it % 3);
  }
  asm volatile("s_waitcnt vmcnt(0)" ::: "memory");
  __builtin_amdgcn_s_barrier();
  COMPUTE3((nk - 1) % 3);

#undef STAGE3
#undef COMPUTE3

  const float* be = bias + (size_t)e * N;
#pragma unroll
  for (int fm = 0; fm < 4; fm++) {
#pragma unroll
    for (int fn = 0; fn < 4; fn++) {
      int col = n0 + wn * 64 + fn * 16 + lrow;
      float bv = be[col];
#pragma unroll
      for (int r = 0; r < 4; r++) {
        int rowt = wm * 64 + fm * 16 + (lane >> 4) * 4 + r;
        int mg = m0 + rowt;
        if (mg < cnt) {
          float v = acc[fm][fn][r] + bv;
          if (ACT == 2) v = gelu_fast(v);
          long orow = base + mg;
          if (SCALE) v *= wslot[orow];
          Out[orow * (long)N + col] = (_Float16)v;
        }
      }
    }
  }
}

// ---------------- fused B: expert GEMM1 (2560) + tcast W2 (16384) ----------------
#define FB_G1 (32 * 80)
#define FB_TC 16384
__global__ __launch_bounds__(256) void fusedB_kernel(
    const _Float16* __restrict__ xh, const _Float16* __restrict__ W1t,
    const float* __restrict__ b1, _Float16* __restrict__ hbuf,
    const int* __restrict__ offsets, const int* __restrict__ toklist,
    const int* __restrict__ tileE, const int* __restrict__ tileM, const int* __restrict__ tileC,
    const float* __restrict__ W2, _Float16* __restrict__ W2t) {
  __shared__ __align__(16) char smem[49152];
  int bid = blockIdx.x;
  if (bid < FB_G1) {
    moe_gemm_body<H_DIM, 2, true, false>(bid >> 5, (bid & 31) * 128, xh, W1t, b1, hbuf,
                                         offsets, toklist, nullptr, tileE, tileM, tileC,
                                         F_DIM, smem);
  } else {
    int idx = bid - FB_G1;
    int nt = idx & 15, kt = (idx >> 4) & 63, e = idx >> 10;
    tcast_body(W2, W2t, F_DIM, H_DIM, e, kt * 64, nt * 64, smem);
  }
}

// expert GEMM2 standalone (K=4096), f16 out with combine-weight scale
__global__ __launch_bounds__(256) void moe_gemm2_kernel(
    const _Float16* __restrict__ hbuf, const _Float16* __restrict__ W2t,
    const float* __restrict__ b2, _Float16* __restrict__ ybuf,
    const int* __restrict__ offsets, const float* __restrict__ wslot,
    const int* __restrict__ tileE, const int* __restrict__ tileM, const int* __restrict__ tileC) {
  __shared__ __align__(16) char smem[49152];
  moe_gemm_body<F_DIM, 0, false, true>(blockIdx.y, blockIdx.x * 128, hbuf, W2t, b2, ybuf,
                                       offsets, nullptr, wslot, tileE, tileM, tileC,
                                       H_DIM, smem);
}

// ---------------- FALLBACK MFMA GEMM (in-flight convert, small ws) ----------------
template <int ACT, bool GATHER, bool OFFS, bool SCALE>
__global__ __launch_bounds__(256) void moe_gemm(
    const _Float16* __restrict__ A, const float* __restrict__ W,
    const float* __restrict__ bias, _Float16* __restrict__ Out,
    const int* __restrict__ offsets, const int* __restrict__ toklist,
    const float* __restrict__ wslot, int M, int N, int K) {
  int e = blockIdx.z;
  int base = 0, cnt = M;
  if (OFFS) { base = offsets[e]; cnt = offsets[e + 1] - base; }
  int m0 = blockIdx.y * 64;
  if (m0 >= cnt) return;
  int n0 = blockIdx.x * 64;
  const float* We = W + (size_t)e * K * N;
  const float* be = bias + (size_t)e * N;

  __shared__ _Float16 As[64][40];
  __shared__ _Float16 Bs[64][40];

  int tid = threadIdx.x;
  int arow = tid >> 2, achk = tid & 3;
  int am_idx = m0 + arow; if (am_idx > cnt - 1) am_idx = cnt - 1;
  long arowg = GATHER ? (long)toklist[base + am_idx] : (long)(base + am_idx);
  const _Float16* Arow = A + arowg * (long)K + achk * 8;

  int brow = tid >> 3, bq = tid & 7;

  floatx4 acc[2][2];
#pragma unroll
  for (int i = 0; i < 2; i++)
#pragma unroll
    for (int j = 0; j < 2; j++) acc[i][j] = (floatx4){0.f, 0.f, 0.f, 0.f};

  int wv = tid >> 6, lane = tid & 63;
  int wm = wv >> 1, wn = wv & 1;
  int lrow = lane & 15, lk = (lane >> 4) * 8;

  for (int k0 = 0; k0 < K; k0 += 32) {
    *reinterpret_cast<f16x8*>(&As[arow][achk * 8]) = *reinterpret_cast<const f16x8*>(Arow + k0);
    const float* wp = We + (size_t)(k0 + brow) * N + n0 + bq * 4;
    floatx4 w0 = *reinterpret_cast<const floatx4*>(wp);
    floatx4 w1 = *reinterpret_cast<const floatx4*>(wp + 32);
#pragma unroll
    for (int i = 0; i < 4; i++) {
      Bs[bq * 4 + i][brow]      = (_Float16)w0[i];
      Bs[32 + bq * 4 + i][brow] = (_Float16)w1[i];
    }
    __syncthreads();

    f16x8 a0 = *reinterpret_cast<const f16x8*>(&As[32 * wm + lrow][lk]);
    f16x8 a1 = *reinterpret_cast<const f16x8*>(&As[32 * wm + 16 + lrow][lk]);
    f16x8 b0 = *reinterpret_cast<const f16x8*>(&Bs[32 * wn + lrow][lk]);
    f16x8 b1 = *reinterpret_cast<const f16x8*>(&Bs[32 * wn + 16 + lrow][lk]);
    acc[0][0] = __builtin_amdgcn_mfma_f32_16x16x32_f16(a0, b0, acc[0][0], 0, 0, 0);
    acc[0][1] = __builtin_amdgcn_mfma_f32_16x16x32_f16(a0, b1, acc[0][1], 0, 0, 0);
    acc[1][0] = __builtin_amdgcn_mfma_f32_16x16x32_f16(a1, b0, acc[1][0], 0, 0, 0);
    acc[1][1] = __builtin_amdgcn_mfma_f32_16x16x32_f16(a1, b1, acc[1][1], 0, 0, 0);
    __syncthreads();
  }

#pragma unroll
  for (int am = 0; am < 2; am++) {
#pragma unroll
    for (int bn = 0; bn < 2; bn++) {
      int col = n0 + 32 * wn + 16 * bn + lrow;
      float bv = be[col];
#pragma unroll
      for (int r = 0; r < 4; r++) {
        int rowt = 32 * wm + 16 * am + (lane >> 4) * 4 + r;
        int mg = m0 + rowt;
        if (mg < cnt) {
          float v = acc[am][bn][r] + bv;
          if (ACT == 2) v = gelu_fast(v);
          long orow = base + mg;
          if (SCALE) v *= wslot[orow];
          Out[orow * (long)N + col] = (_Float16)v;
        }
      }
    }
  }
}

__global__ void cast_x_kernel(const float* __restrict__ x, _Float16* __restrict__ xh) {
  cast_x_body(blockIdx.x, x, xh);
}

__global__ __launch_bounds__(256) void router_gemm1_kernel(
    const float* __restrict__ x, const float* __restrict__ Wr1,
    const float* __restrict__ br1, float* __restrict__ hrf) {
  __shared__ __align__(16) char smem[20480];
  router_gemm1_body(blockIdx.y * 64, blockIdx.x * 64, x, Wr1, br1, hrf, smem);
}

// ---------------- launch ----------------
extern "C" void kernel_launch(void* const* d_in, const int* in_sizes, int n_in,
                              void* d_out, int out_size, void* d_ws, size_t ws_size,
                              hipStream_t stream) {
  const float* x   = (const float*)d_in[0];
  const float* Wr1 = (const float*)d_in[1];
  const float* br1 = (const float*)d_in[2];
  const float* Wr2 = (const float*)d_in[3];
  const float* br2 = (const float*)d_in[4];
  const float* W1  = (const float*)d_in[5];
  const float* b1  = (const float*)d_in[6];
  const float* W2  = (const float*)d_in[7];
  const float* b2  = (const float*)d_in[8];
  float* out = (float*)d_out;

  char* ws = (char*)d_ws;
  float* logits = (float*)(ws + LOGIT_OFF);
  int*   offs   = (int*)(ws + OFFS_OFF);
  int*   toks   = (int*)(ws + TOKS_OFF);
  float* wsl    = (float*)(ws + WSL_OFF);
  int*   stk    = (int*)(ws + STK_OFF);
  int*   tileE  = (int*)(ws + TILEE_OFF);
  int*   tileM  = (int*)(ws + TILEM_OFF);
  int*   tileC  = (int*)(ws + TILEC_OFF);
  _Float16* xh   = (_Float16*)(ws + XH_OFF);
  float*    hrf  = (float*)(ws + HBUF_OFF);
  _Float16* hbuf = (_Float16*)(ws + HBUF_OFF);
  _Float16* ybuf = (_Float16*)(ws + YBUF_OFF);
  _Float16* W1t  = (_Float16*)(ws + W1T_OFF);
  _Float16* W2t  = (_Float16*)(ws + W2T_OFF);

  bool fast = ws_size >= WS_NEED_FAST;

  if (fast) {
    fusedA_kernel<<<FA_RG + FA_TC + FA_CX, 256, 0, stream>>>(x, Wr1, br1, hrf, W1, W1t, xh);
  } else {
    cast_x_kernel<<<(T_TOK * H_DIM / 8) / 256, 256, 0, stream>>>(x, xh);
    router_gemm1_kernel<<<dim3(H_DIM / 64, T_TOK / 64), 256, 0, stream>>>(x, Wr1, br1, hrf);
  }

  router_logits_kernel<<<T_TOK / 4, 256, 0, stream>>>(hrf, Wr2, br2, logits);
  routing_kernel<<<1, 1024, 0, stream>>>(logits, offs, toks, wsl, stk, tileE, tileM, tileC);

  if (fast) {
    fusedB_kernel<<<FB_G1 + FB_TC, 256, 0, stream>>>(xh, W1t, b1, hbuf, offs, toks,
                                                     tileE, tileM, tileC, W2, W2t);
    moe_gemm2_kernel<<<dim3(H_DIM / 128, 80), 256, 0, stream>>>(hbuf, W2t, b2, ybuf, offs, wsl,
                                                                tileE, tileM, tileC);
  } else {
    moe_gemm<2, true, true, false><<<dim3(F_DIM / 64, T_TOK / 64, E_NUM), 256, 0, stream>>>(
        xh, W1, b1, hbuf, offs, toks, nullptr, T_TOK, F_DIM, H_DIM);
    moe_gemm<0, false, true, true><<<dim3(H_DIM / 64, T_TOK / 64, E_NUM), 256, 0, stream>>>(
        hbuf, W2, b2, ybuf, offs, nullptr, wsl, T_TOK, H_DIM, F_DIM);
  }

  combine_kernel<<<(T_TOK * H_DIM / 8) / 256, 256, 0, stream>>>(ybuf, stk, out);
}